// Round 1
// baseline (809.248 us; speedup 1.0000x reference)
//
#include <hip/hip_runtime.h>
#include <hip/hip_bf16.h>
#include <math.h>

#define NN 100000      // nodes
#define NE 1000000     // edges
#define NB 1024        // graphs
#define HD 64          // hidden dim

// ---------------------------------------------------------------------------
// Detect whether the bool inputs were pushed as 1-byte bools or int32.
// Flags are random 0/1: as uint8, ~50% of the first NN bytes are nonzero;
// as int32 (little-endian 0/1), only ~12.5% of the first NN bytes are nonzero.
__global__ void detect_bool_kernel(const unsigned char* __restrict__ p,
                                   int nbytes, int* __restrict__ flag) {
    __shared__ int cnt_s[256];
    int c = 0;
    for (int i = threadIdx.x; i < nbytes; i += 256) c += (p[i] != 0);
    cnt_s[threadIdx.x] = c;
    __syncthreads();
    for (int s = 128; s > 0; s >>= 1) {
        if (threadIdx.x < s) cnt_s[threadIdx.x] += cnt_s[threadIdx.x + s];
        __syncthreads();
    }
    if (threadIdx.x == 0) flag[0] = (cnt_s[0] * 4 > nbytes) ? 1 : 0;
}

// feat[i] = [u, v] as float
__global__ void feat_kernel(const void* __restrict__ u, const void* __restrict__ v,
                            const int* __restrict__ flag, float* __restrict__ feat,
                            int n) {
    int i = blockIdx.x * blockDim.x + threadIdx.x;
    if (i >= n) return;
    float fu, fv;
    if (flag[0]) {
        fu = ((const unsigned char*)u)[i] ? 1.0f : 0.0f;
        fv = ((const unsigned char*)v)[i] ? 1.0f : 0.0f;
    } else {
        fu = ((const int*)u)[i] ? 1.0f : 0.0f;
        fv = ((const int*)v)[i] ? 1.0f : 0.0f;
    }
    feat[2 * i]     = fu;
    feat[2 * i + 1] = fv;
}

// agg0[dst] += feat[src]   (N x 2)
__global__ void gin_edge0_kernel(const int* __restrict__ src, const int* __restrict__ dst,
                                 const float* __restrict__ feat, float* __restrict__ agg0,
                                 int e) {
    int ed = blockIdx.x * blockDim.x + threadIdx.x;
    if (ed >= e) return;
    int s = src[ed], d = dst[ed];
    float f0 = feat[2 * s], f1 = feat[2 * s + 1];
    if (f0 != 0.0f) atomicAdd(&agg0[2 * d],     f0);
    if (f1 != 0.0f) atomicAdd(&agg0[2 * d + 1], f1);
}

// h0 = relu(((1+eps0)*feat + agg0) @ W0 + b0)   -- W0 is 2x64
__global__ void gin_node0_kernel(const float* __restrict__ feat, const float* __restrict__ agg0,
                                 const float* __restrict__ W0, const float* __restrict__ b0,
                                 const float* __restrict__ epsp, float* __restrict__ hout,
                                 int n) {
    int idx = blockIdx.x * blockDim.x + threadIdx.x;
    int i = idx >> 6, j = idx & 63;
    if (i >= n) return;
    float e = 1.0f + epsp[0];
    float z0 = e * feat[2 * i]     + agg0[2 * i];
    float z1 = e * feat[2 * i + 1] + agg0[2 * i + 1];
    float acc = fmaf(z0, W0[j], fmaf(z1, W0[64 + j], b0[j]));
    hout[idx] = fmaxf(acc, 0.0f);
}

// agg[dst,:] += h[src,:]   (64 lanes per edge)
__global__ void gin_edge_kernel(const int* __restrict__ src, const int* __restrict__ dst,
                                const float* __restrict__ h, float* __restrict__ agg,
                                int e) {
    int idx = blockIdx.x * blockDim.x + threadIdx.x;
    int ed = idx >> 6, lane = idx & 63;
    if (ed >= e) return;
    int s = src[ed], d = dst[ed];
    atomicAdd(&agg[(size_t)d * 64 + lane], h[(size_t)s * 64 + lane]);
}

// hout = relu(((1+eps)*hin + agg) @ W + b); safe for hout == hin (z staged in LDS)
__global__ __launch_bounds__(256) void gin_node_kernel(
        const float* __restrict__ hin, const float* __restrict__ agg,
        const float* __restrict__ W, const float* __restrict__ b,
        const float* __restrict__ epsp, float* __restrict__ hout, int n) {
    __shared__ float Ws[64 * 64];
    __shared__ float zs[4][64];
    const int tid = threadIdx.x;
    const int grp = tid >> 6;   // 0..3 (node within block)
    const int lane = tid & 63;
    for (int k = tid; k < 64 * 64; k += 256) Ws[k] = W[k];
    const float e1 = 1.0f + epsp[0];
    const float bj = b[lane];
    __syncthreads();
    const int nodesPerIter = gridDim.x * 4;
    const int iters = (n + nodesPerIter - 1) / nodesPerIter;
    for (int it = 0; it < iters; ++it) {
        int i = it * nodesPerIter + blockIdx.x * 4 + grp;
        bool valid = (i < n);
        float zk = 0.0f;
        if (valid) zk = fmaf(e1, hin[(size_t)i * 64 + lane], agg[(size_t)i * 64 + lane]);
        zs[grp][lane] = zk;
        __syncthreads();
        if (valid) {
            float acc = bj;
            #pragma unroll
            for (int k = 0; k < 64; ++k)
                acc = fmaf(zs[grp][k], Ws[k * 64 + lane], acc);
            hout[(size_t)i * 64 + lane] = fmaxf(acc, 0.0f);
        }
        __syncthreads();
    }
}

// per-graph sums + counts
__global__ void pool_kernel(const float* __restrict__ h, const int* __restrict__ n2g,
                            float* __restrict__ sums, float* __restrict__ cnts, int n) {
    int idx = blockIdx.x * blockDim.x + threadIdx.x;
    int i = idx >> 6, j = idx & 63;
    if (i >= n) return;
    int g = n2g[i];
    atomicAdd(&sums[(size_t)g * 64 + j], h[idx]);
    if (j == 0) atomicAdd(&cnts[g], 1.0f);
}

// out[g] = sigmoid(relu(hg @ Ws1 + bs1) @ Ws2 + bs2)
__global__ __launch_bounds__(64) void scorer_kernel(
        const float* __restrict__ sums, const float* __restrict__ cnts,
        const float* __restrict__ Ws1, const float* __restrict__ bs1,
        const float* __restrict__ Ws2, const float* __restrict__ bs2,
        float* __restrict__ out) {
    int g = blockIdx.x, j = threadIdx.x;
    __shared__ float hgs[64];
    float c = cnts[g];
    hgs[j] = sums[(size_t)g * 64 + j] / fmaxf(c, 1.0f);
    __syncthreads();
    float acc = bs1[j];
    #pragma unroll
    for (int k = 0; k < 64; ++k)
        acc = fmaf(hgs[k], Ws1[k * 64 + j], acc);
    float z = fmaxf(acc, 0.0f) * Ws2[j];
    #pragma unroll
    for (int off = 32; off > 0; off >>= 1) z += __shfl_xor(z, off);
    if (j == 0) out[g] = 1.0f / (1.0f + expf(-(z + bs2[0])));
}

extern "C" void kernel_launch(void* const* d_in, const int* in_sizes, int n_in,
                              void* d_out, int out_size, void* d_ws, size_t ws_size,
                              hipStream_t stream) {
    const void*  u_flag = d_in[0];
    const void*  v_flag = d_in[1];
    const int*   src    = (const int*)d_in[2];
    const int*   dst    = (const int*)d_in[3];
    const int*   n2g    = (const int*)d_in[4];
    const float* W0     = (const float*)d_in[5];
    const float* b0     = (const float*)d_in[6];
    const float* eps0   = (const float*)d_in[7];
    const float* W1     = (const float*)d_in[8];
    const float* b1     = (const float*)d_in[9];
    const float* eps1   = (const float*)d_in[10];
    const float* W2     = (const float*)d_in[11];
    const float* b2     = (const float*)d_in[12];
    const float* eps2   = (const float*)d_in[13];
    const float* Ws1    = (const float*)d_in[14];
    const float* bs1    = (const float*)d_in[15];
    const float* Ws2    = (const float*)d_in[16];
    const float* bs2    = (const float*)d_in[17];
    float* out = (float*)d_out;

    // workspace layout
    float* feat = (float*)d_ws;                       // NN*2
    float* agg0 = feat + (size_t)NN * 2;              // NN*2
    float* hbuf = agg0 + (size_t)NN * 2;              // NN*64 (in-place across layers)
    float* agg  = hbuf + (size_t)NN * 64;             // NN*64
    float* sums = agg  + (size_t)NN * 64;             // NB*64
    float* cnts = sums + (size_t)NB * 64;             // NB
    int*   flag = (int*)(cnts + NB);                  // 1

    const int B256 = 256;

    // bool-layout detection + feature build
    detect_bool_kernel<<<1, 256, 0, stream>>>((const unsigned char*)u_flag, NN, flag);
    feat_kernel<<<(NN + B256 - 1) / B256, B256, 0, stream>>>(u_flag, v_flag, flag, feat, NN);

    // ---- layer 0 (feat dim 2) ----
    hipMemsetAsync(agg0, 0, (size_t)NN * 2 * sizeof(float), stream);
    gin_edge0_kernel<<<(NE + B256 - 1) / B256, B256, 0, stream>>>(src, dst, feat, agg0, NE);
    gin_node0_kernel<<<(NN * 64 + B256 - 1) / B256, B256, 0, stream>>>(
        feat, agg0, W0, b0, eps0, hbuf, NN);

    // ---- layer 1 ----
    hipMemsetAsync(agg, 0, (size_t)NN * 64 * sizeof(float), stream);
    gin_edge_kernel<<<(int)(((size_t)NE * 64 + B256 - 1) / B256), B256, 0, stream>>>(
        src, dst, hbuf, agg, NE);
    gin_node_kernel<<<1024, 256, 0, stream>>>(hbuf, agg, W1, b1, eps1, hbuf, NN);

    // ---- layer 2 ----
    hipMemsetAsync(agg, 0, (size_t)NN * 64 * sizeof(float), stream);
    gin_edge_kernel<<<(int)(((size_t)NE * 64 + B256 - 1) / B256), B256, 0, stream>>>(
        src, dst, hbuf, agg, NE);
    gin_node_kernel<<<1024, 256, 0, stream>>>(hbuf, agg, W2, b2, eps2, hbuf, NN);

    // ---- mean pool + scorer ----
    hipMemsetAsync(sums, 0, ((size_t)NB * 64 + NB) * sizeof(float), stream);
    pool_kernel<<<(NN * 64 + B256 - 1) / B256, B256, 0, stream>>>(hbuf, n2g, sums, cnts, NN);
    scorer_kernel<<<NB, 64, 0, stream>>>(sums, cnts, Ws1, bs1, Ws2, bs2, out);
}

// Round 4
// 675.594 us; speedup vs baseline: 1.1978x; 1.1978x over previous
//
#include <hip/hip_runtime.h>
#include <hip/hip_bf16.h>
#include <math.h>

#define NN 100000      // nodes
#define NE 1000000     // edges
#define NB 1024        // graphs
#define SCAN_B 1024

// ---------------------------------------------------------------------------
// Detect whether the bool inputs were pushed as 1-byte bools or int32.
__global__ void detect_bool_kernel(const unsigned char* __restrict__ p,
                                   int nbytes, int* __restrict__ flag) {
    __shared__ int cnt_s[256];
    int c = 0;
    for (int i = threadIdx.x; i < nbytes; i += 256) c += (p[i] != 0);
    cnt_s[threadIdx.x] = c;
    __syncthreads();
    for (int s = 128; s > 0; s >>= 1) {
        if (threadIdx.x < s) cnt_s[threadIdx.x] += cnt_s[threadIdx.x + s];
        __syncthreads();
    }
    if (threadIdx.x == 0) flag[0] = (cnt_s[0] * 4 > nbytes) ? 1 : 0;
}

__global__ void feat_kernel(const void* __restrict__ u, const void* __restrict__ v,
                            const int* __restrict__ flag, float2* __restrict__ feat,
                            int n) {
    int i = blockIdx.x * blockDim.x + threadIdx.x;
    if (i >= n) return;
    float fu, fv;
    if (flag[0]) {
        fu = ((const unsigned char*)u)[i] ? 1.0f : 0.0f;
        fv = ((const unsigned char*)v)[i] ? 1.0f : 0.0f;
    } else {
        fu = ((const int*)u)[i] ? 1.0f : 0.0f;
        fv = ((const int*)v)[i] ? 1.0f : 0.0f;
    }
    feat[i] = make_float2(fu, fv);
}

// ---------------- CSR build (per call) -----------------
__global__ void hist_kernel(const int* __restrict__ dst, int* __restrict__ deg, int e) {
    int i = blockIdx.x * blockDim.x + threadIdx.x;
    if (i < e) atomicAdd(&deg[dst[i]], 1);
}

__global__ void scan1_kernel(int* __restrict__ data, int* __restrict__ bsum, int n) {
    __shared__ int s[SCAN_B];
    int tid = threadIdx.x, gid = blockIdx.x * SCAN_B + tid;
    int v = (gid < n) ? data[gid] : 0;
    s[tid] = v;
    __syncthreads();
    for (int off = 1; off < SCAN_B; off <<= 1) {
        int t = (tid >= off) ? s[tid - off] : 0;
        __syncthreads();
        s[tid] += t;
        __syncthreads();
    }
    if (gid < n) data[gid] = s[tid] - v;           // exclusive (pre-offset)
    if (tid == SCAN_B - 1) bsum[blockIdx.x] = s[tid];
}

__global__ void scan2_kernel(int* __restrict__ bsum, int nb) {
    __shared__ int s[128];
    int tid = threadIdx.x;
    int v = (tid < nb) ? bsum[tid] : 0;
    s[tid] = v;
    __syncthreads();
    for (int off = 1; off < 128; off <<= 1) {
        int t = (tid >= off) ? s[tid - off] : 0;
        __syncthreads();
        s[tid] += t;
        __syncthreads();
    }
    if (tid < nb) bsum[tid] = s[tid] - v;          // exclusive block offsets
}

__global__ void scan3_kernel(int* __restrict__ data, const int* __restrict__ bsum,
                             int* __restrict__ cursor, int n, int total) {
    int gid = blockIdx.x * SCAN_B + threadIdx.x;
    if (gid < n) {
        int r = data[gid] + bsum[gid >> 10];
        data[gid] = r;
        cursor[gid] = r;
    }
    if (gid == n) data[n] = total;
}

__global__ void scatter_kernel(const int* __restrict__ src, const int* __restrict__ dst,
                               int* __restrict__ cursor, int* __restrict__ esrc, int e) {
    int i = blockIdx.x * blockDim.x + threadIdx.x;
    if (i < e) {
        int pos = atomicAdd(&cursor[dst[i]], 1);
        esrc[pos] = src[i];
    }
}

__global__ void cnt_kernel(const int* __restrict__ n2g, float* __restrict__ cnts, int n) {
    int i = blockIdx.x * blockDim.x + threadIdx.x;
    if (i < n) atomicAdd(&cnts[n2g[i]], 1.0f);
}

// ---------------- fused GIN layers (gather-based, no float atomics) --------
// layer 0: feat dim 2 -> 64
__global__ __launch_bounds__(256) void gin_layer0_kernel(
        const int* __restrict__ rowptr, const int* __restrict__ esrc,
        const float2* __restrict__ feat,
        const float* __restrict__ W0, const float* __restrict__ b0,
        const float* __restrict__ epsp, __hip_bfloat16* __restrict__ hout) {
    const int lane = threadIdx.x & 63;
    const int wid = (blockIdx.x * blockDim.x + threadIdx.x) >> 6;
    const int nwaves = (gridDim.x * blockDim.x) >> 6;
    const int per = (NN + nwaves - 1) / nwaves;
    int i0 = wid * per, i1 = min(NN, i0 + per);
    const float w00 = W0[lane], w01 = W0[64 + lane], bj = b0[lane];
    const float ep = 1.0f + epsp[0];
    for (int i = i0; i < i1; ++i) {
        int e0 = rowptr[i], eE = rowptr[i + 1];
        float2 f = feat[i];
        float z0 = ep * f.x, z1 = ep * f.y;
        for (int e = e0; e < eE; ++e) {
            float2 g = feat[esrc[e]];
            z0 += g.x; z1 += g.y;
        }
        float o = fmaxf(fmaf(z0, w00, fmaf(z1, w01, bj)), 0.0f);
        hout[(size_t)i * 64 + lane] = __float2bfloat16(o);
    }
}

// layers 1/2: 64 -> 64. W staged in LDS (scratch-free), z broadcast via shfl.
// DO_POOL fuses the mean-pool sum accumulation.
template <int DO_POOL>
__global__ __launch_bounds__(256) void gin_layer_kernel(
        const int* __restrict__ rowptr, const int* __restrict__ esrc,
        const __hip_bfloat16* __restrict__ hin,
        const float* __restrict__ W, const float* __restrict__ b,
        const float* __restrict__ epsp, __hip_bfloat16* __restrict__ hout,
        const int* __restrict__ n2g, float* __restrict__ sums) {
    __shared__ float Ws[64 * 64];
    const int tid = threadIdx.x;
    const int lane = tid & 63;
    for (int k = tid; k < 64 * 64; k += 256) Ws[k] = W[k];
    __syncthreads();
    const int wid = (blockIdx.x * blockDim.x + tid) >> 6;
    const int nwaves = (gridDim.x * blockDim.x) >> 6;
    const float ep = 1.0f + epsp[0];
    const float bj = b[lane];
    const int per = (NN + nwaves - 1) / nwaves;
    int i0 = wid * per, i1 = min(NN, i0 + per);
    float pacc = 0.0f;
    int curg = -1;
    for (int i = i0; i < i1; ++i) {
        int e0 = rowptr[i], eE = rowptr[i + 1];
        float acc = 0.0f;
        for (int e = e0; e < eE; ++e) {
            int s = esrc[e];
            acc += __bfloat162float(hin[(size_t)s * 64 + lane]);
        }
        float z = fmaf(ep, __bfloat162float(hin[(size_t)i * 64 + lane]), acc);
        // 64x64 GEMV: o_j = b_j + sum_k z_k * W[k][j]
        float o0 = bj, o1 = 0.0f, o2 = 0.0f, o3 = 0.0f;
        #pragma unroll
        for (int k = 0; k < 64; k += 4) {
            o0 = fmaf(__shfl(z, k),     Ws[(k    ) * 64 + lane], o0);
            o1 = fmaf(__shfl(z, k + 1), Ws[(k + 1) * 64 + lane], o1);
            o2 = fmaf(__shfl(z, k + 2), Ws[(k + 2) * 64 + lane], o2);
            o3 = fmaf(__shfl(z, k + 3), Ws[(k + 3) * 64 + lane], o3);
        }
        float o = fmaxf((o0 + o1) + (o2 + o3), 0.0f);
        hout[(size_t)i * 64 + lane] = __float2bfloat16(o);
        if (DO_POOL) {
            int g = n2g[i];
            if (g != curg) {
                if (curg >= 0) atomicAdd(&sums[(size_t)curg * 64 + lane], pacc);
                curg = g;
                pacc = 0.0f;
            }
            pacc += o;
        }
    }
    if (DO_POOL && curg >= 0) atomicAdd(&sums[(size_t)curg * 64 + lane], pacc);
}

// out[g] = sigmoid(relu(mean_h @ Ws1 + bs1) @ Ws2 + bs2)
__global__ __launch_bounds__(64) void scorer_kernel(
        const float* __restrict__ sums, const float* __restrict__ cnts,
        const float* __restrict__ Ws1, const float* __restrict__ bs1,
        const float* __restrict__ Ws2, const float* __restrict__ bs2,
        float* __restrict__ out) {
    int g = blockIdx.x, j = threadIdx.x;
    __shared__ float hgs[64];
    float c = cnts[g];
    hgs[j] = sums[(size_t)g * 64 + j] / fmaxf(c, 1.0f);
    __syncthreads();
    float acc = bs1[j];
    #pragma unroll
    for (int k = 0; k < 64; ++k)
        acc = fmaf(hgs[k], Ws1[k * 64 + j], acc);
    float z = fmaxf(acc, 0.0f) * Ws2[j];
    #pragma unroll
    for (int off = 32; off > 0; off >>= 1) z += __shfl_xor(z, off);
    if (j == 0) out[g] = 1.0f / (1.0f + expf(-(z + bs2[0])));
}

extern "C" void kernel_launch(void* const* d_in, const int* in_sizes, int n_in,
                              void* d_out, int out_size, void* d_ws, size_t ws_size,
                              hipStream_t stream) {
    const void*  u_flag = d_in[0];
    const void*  v_flag = d_in[1];
    const int*   src    = (const int*)d_in[2];
    const int*   dst    = (const int*)d_in[3];
    const int*   n2g    = (const int*)d_in[4];
    const float* W0     = (const float*)d_in[5];
    const float* b0     = (const float*)d_in[6];
    const float* eps0   = (const float*)d_in[7];
    const float* W1     = (const float*)d_in[8];
    const float* b1     = (const float*)d_in[9];
    const float* eps1   = (const float*)d_in[10];
    const float* W2     = (const float*)d_in[11];
    const float* b2     = (const float*)d_in[12];
    const float* eps2   = (const float*)d_in[13];
    const float* Ws1    = (const float*)d_in[14];
    const float* bs1    = (const float*)d_in[15];
    const float* Ws2    = (const float*)d_in[16];
    const float* bs2    = (const float*)d_in[17];
    float* out = (float*)d_out;

    // ---- workspace layout (int = 4-byte units), NON-OVERLAPPING ----
    // h_a / h_b are NN*64 bf16 = 6.4M elems * 2B = 12.8 MB = 3,200,000 ints EACH.
    int*    ws     = (int*)d_ws;
    int*    rowptr = ws;                                    // [0,       100001)
    int*    cursor = ws + 100004;                           // [100004,  200004)
    int*    bsum   = ws + 200004;                           // [200004,  200132)
    int*    flag   = ws + 200132;                           // [200132,  200136)
    float2* feat   = (float2*)(ws + 200136);                // [200136,  400136)  NN float2
    __hip_bfloat16* h_a = (__hip_bfloat16*)(ws + 400136);   // [400136,  3600136)
    __hip_bfloat16* h_b = (__hip_bfloat16*)(ws + 3600136);  // [3600136, 6800136)
    int*    esrc   = ws + 6800136;                          // [6800136, 7800136)
    float*  sums   = (float*)(ws + 7800136);                // [7800136, 7865672)
    float*  cnts   = (float*)(ws + 7865672);                // [7865672, 7866696)

    const int B256 = 256;
    const int nb1 = (NN + SCAN_B - 1) / SCAN_B;             // 98

    // feature build + counts
    detect_bool_kernel<<<1, 256, 0, stream>>>((const unsigned char*)u_flag, NN, flag);
    feat_kernel<<<(NN + B256 - 1) / B256, B256, 0, stream>>>(u_flag, v_flag, flag, feat, NN);
    hipMemsetAsync(sums, 0, ((size_t)NB * 64 + NB) * sizeof(float), stream);
    cnt_kernel<<<(NN + B256 - 1) / B256, B256, 0, stream>>>(n2g, cnts, NN);

    // CSR build: deg -> exclusive scan -> scatter by cursor
    hipMemsetAsync(rowptr, 0, (size_t)(NN + 1) * sizeof(int), stream);
    hist_kernel<<<(NE + B256 - 1) / B256, B256, 0, stream>>>(dst, rowptr, NE);
    scan1_kernel<<<nb1, SCAN_B, 0, stream>>>(rowptr, bsum, NN);
    scan2_kernel<<<1, 128, 0, stream>>>(bsum, nb1);
    scan3_kernel<<<(NN + 1 + SCAN_B - 1) / SCAN_B, SCAN_B, 0, stream>>>(rowptr, bsum, cursor, NN, NE);
    scatter_kernel<<<(NE + B256 - 1) / B256, B256, 0, stream>>>(src, dst, cursor, esrc, NE);

    // fused GIN layers
    gin_layer0_kernel<<<1024, 256, 0, stream>>>(rowptr, esrc, feat, W0, b0, eps0, h_a);
    gin_layer_kernel<0><<<1024, 256, 0, stream>>>(rowptr, esrc, h_a, W1, b1, eps1, h_b,
                                                  n2g, sums);
    gin_layer_kernel<1><<<1024, 256, 0, stream>>>(rowptr, esrc, h_b, W2, b2, eps2, h_a,
                                                  n2g, sums);

    // scorer
    scorer_kernel<<<NB, 64, 0, stream>>>(sums, cnts, Ws1, bs1, Ws2, bs2, out);
}

// Round 5
// 448.112 us; speedup vs baseline: 1.8059x; 1.5076x over previous
//
#include <hip/hip_runtime.h>
#include <hip/hip_bf16.h>
#include <math.h>

#define NN 100000      // nodes
#define NE 1000000     // edges
#define NB 1024        // graphs
#define SCAN_B 1024

// ---------------------------------------------------------------------------
// Detect whether the bool inputs were pushed as 1-byte bools or int32.
__global__ void detect_bool_kernel(const unsigned char* __restrict__ p,
                                   int nbytes, int* __restrict__ flag) {
    __shared__ int cnt_s[256];
    int c = 0;
    for (int i = threadIdx.x; i < nbytes; i += 256) c += (p[i] != 0);
    cnt_s[threadIdx.x] = c;
    __syncthreads();
    for (int s = 128; s > 0; s >>= 1) {
        if (threadIdx.x < s) cnt_s[threadIdx.x] += cnt_s[threadIdx.x + s];
        __syncthreads();
    }
    if (threadIdx.x == 0) flag[0] = (cnt_s[0] * 4 > nbytes) ? 1 : 0;
}

__global__ void feat_kernel(const void* __restrict__ u, const void* __restrict__ v,
                            const int* __restrict__ flag, float2* __restrict__ feat,
                            int n) {
    int i = blockIdx.x * blockDim.x + threadIdx.x;
    if (i >= n) return;
    float fu, fv;
    if (flag[0]) {
        fu = ((const unsigned char*)u)[i] ? 1.0f : 0.0f;
        fv = ((const unsigned char*)v)[i] ? 1.0f : 0.0f;
    } else {
        fu = ((const int*)u)[i] ? 1.0f : 0.0f;
        fv = ((const int*)v)[i] ? 1.0f : 0.0f;
    }
    feat[i] = make_float2(fu, fv);
}

// ---------------- CSR build (per call) -----------------
__global__ void hist_kernel(const int* __restrict__ dst, int* __restrict__ deg, int e) {
    int i = blockIdx.x * blockDim.x + threadIdx.x;
    if (i < e) atomicAdd(&deg[dst[i]], 1);
}

__global__ void scan1_kernel(int* __restrict__ data, int* __restrict__ bsum, int n) {
    __shared__ int s[SCAN_B];
    int tid = threadIdx.x, gid = blockIdx.x * SCAN_B + tid;
    int v = (gid < n) ? data[gid] : 0;
    s[tid] = v;
    __syncthreads();
    for (int off = 1; off < SCAN_B; off <<= 1) {
        int t = (tid >= off) ? s[tid - off] : 0;
        __syncthreads();
        s[tid] += t;
        __syncthreads();
    }
    if (gid < n) data[gid] = s[tid] - v;           // exclusive (pre-offset)
    if (tid == SCAN_B - 1) bsum[blockIdx.x] = s[tid];
}

__global__ void scan2_kernel(int* __restrict__ bsum, int nb) {
    __shared__ int s[128];
    int tid = threadIdx.x;
    int v = (tid < nb) ? bsum[tid] : 0;
    s[tid] = v;
    __syncthreads();
    for (int off = 1; off < 128; off <<= 1) {
        int t = (tid >= off) ? s[tid - off] : 0;
        __syncthreads();
        s[tid] += t;
        __syncthreads();
    }
    if (tid < nb) bsum[tid] = s[tid] - v;          // exclusive block offsets
}

__global__ void scan3_kernel(int* __restrict__ data, const int* __restrict__ bsum,
                             int* __restrict__ cursor, int n, int total) {
    int gid = blockIdx.x * SCAN_B + threadIdx.x;
    if (gid < n) {
        int r = data[gid] + bsum[gid >> 10];
        data[gid] = r;
        cursor[gid] = r;
    }
    if (gid == n) data[n] = total;
}

__global__ void scatter_kernel(const int* __restrict__ src, const int* __restrict__ dst,
                               int* __restrict__ cursor, int* __restrict__ esrc, int e) {
    int i = blockIdx.x * blockDim.x + threadIdx.x;
    if (i < e) {
        int pos = atomicAdd(&cursor[dst[i]], 1);
        esrc[pos] = src[i];
    }
}

__global__ void cnt_kernel(const int* __restrict__ n2g, float* __restrict__ cnts, int n) {
    int i = blockIdx.x * blockDim.x + threadIdx.x;
    if (i < n) atomicAdd(&cnts[n2g[i]], 1.0f);
}

// ---------------- fused GIN layers (gather-based, no float atomics) --------
// layer 0: feat dim 2 -> 64. Lane-parallel edge gather + butterfly reduce.
__global__ __launch_bounds__(256) void gin_layer0_kernel(
        const int* __restrict__ rowptr, const int* __restrict__ esrc,
        const float2* __restrict__ feat,
        const float* __restrict__ W0, const float* __restrict__ b0,
        const float* __restrict__ epsp, __hip_bfloat16* __restrict__ hout) {
    const int lane = threadIdx.x & 63;
    const int wid = (blockIdx.x * blockDim.x + threadIdx.x) >> 6;
    const int nwaves = (gridDim.x * blockDim.x) >> 6;
    const int per = (NN + nwaves - 1) / nwaves;
    int i0 = wid * per, i1 = min(NN, i0 + per);
    const float w00 = W0[lane], w01 = W0[64 + lane], bj = b0[lane];
    const float ep = 1.0f + epsp[0];
    for (int i = i0; i < i1; ++i) {
        int e0 = rowptr[i], eE = rowptr[i + 1];
        float a0 = 0.0f, a1 = 0.0f;
        for (int ec = e0; ec < eE; ec += 64) {
            bool valid = (ec + lane < eE);
            int s = valid ? esrc[ec + lane] : 0;
            float2 g = feat[s];                 // parallel 8B gathers, one per lane
            a0 += valid ? g.x : 0.0f;
            a1 += valid ? g.y : 0.0f;
        }
        #pragma unroll
        for (int off = 32; off > 0; off >>= 1) {
            a0 += __shfl_xor(a0, off);
            a1 += __shfl_xor(a1, off);
        }
        float2 f = feat[i];
        float z0 = fmaf(ep, f.x, a0), z1 = fmaf(ep, f.y, a1);
        float o = fmaxf(fmaf(z0, w00, fmaf(z1, w01, bj)), 0.0f);
        hout[(size_t)i * 64 + lane] = __float2bfloat16(o);
    }
}

// layers 1/2: 64 -> 64. W in LDS; lane-batched edge indices, readlane-broadcast
// gathers (all of a node's gathers issue independently -> deep MLP).
// DO_POOL fuses the mean-pool sum accumulation.
template <int DO_POOL>
__global__ __launch_bounds__(256) void gin_layer_kernel(
        const int* __restrict__ rowptr, const int* __restrict__ esrc,
        const __hip_bfloat16* __restrict__ hin,
        const float* __restrict__ W, const float* __restrict__ b,
        const float* __restrict__ epsp, __hip_bfloat16* __restrict__ hout,
        const int* __restrict__ n2g, float* __restrict__ sums) {
    __shared__ float Ws[64 * 64];
    const int tid = threadIdx.x;
    const int lane = tid & 63;
    for (int k = tid; k < 64 * 64; k += 256) Ws[k] = W[k];
    __syncthreads();
    const int wid = (blockIdx.x * blockDim.x + tid) >> 6;
    const int nwaves = (gridDim.x * blockDim.x) >> 6;
    const float ep = 1.0f + epsp[0];
    const float bj = b[lane];
    const int per = (NN + nwaves - 1) / nwaves;
    int i0 = wid * per, i1 = min(NN, i0 + per);
    float pacc = 0.0f;
    int curg = -1;
    for (int i = i0; i < i1; ++i) {
        int e0 = rowptr[i], eE = rowptr[i + 1];
        float a0 = 0.0f, a1 = 0.0f, a2 = 0.0f, a3 = 0.0f;
        for (int ec = e0; ec < eE; ec += 64) {
            int n = min(eE - ec, 64);
            int sidx = (ec + lane < eE) ? esrc[ec + lane] : 0;  // one coalesced load
            int k = 0;
            for (; k + 4 <= n; k += 4) {
                int s0 = __builtin_amdgcn_readlane(sidx, k);
                int s1 = __builtin_amdgcn_readlane(sidx, k + 1);
                int s2 = __builtin_amdgcn_readlane(sidx, k + 2);
                int s3 = __builtin_amdgcn_readlane(sidx, k + 3);
                a0 += __bfloat162float(hin[(size_t)s0 * 64 + lane]);
                a1 += __bfloat162float(hin[(size_t)s1 * 64 + lane]);
                a2 += __bfloat162float(hin[(size_t)s2 * 64 + lane]);
                a3 += __bfloat162float(hin[(size_t)s3 * 64 + lane]);
            }
            for (; k < n; ++k) {
                int s0 = __builtin_amdgcn_readlane(sidx, k);
                a0 += __bfloat162float(hin[(size_t)s0 * 64 + lane]);
            }
        }
        float acc = (a0 + a1) + (a2 + a3);
        float z = fmaf(ep, __bfloat162float(hin[(size_t)i * 64 + lane]), acc);
        // 64x64 GEMV: o_j = b_j + sum_k z_k * W[k][j]
        float o0 = bj, o1 = 0.0f, o2 = 0.0f, o3 = 0.0f;
        #pragma unroll
        for (int k = 0; k < 64; k += 4) {
            o0 = fmaf(__shfl(z, k),     Ws[(k    ) * 64 + lane], o0);
            o1 = fmaf(__shfl(z, k + 1), Ws[(k + 1) * 64 + lane], o1);
            o2 = fmaf(__shfl(z, k + 2), Ws[(k + 2) * 64 + lane], o2);
            o3 = fmaf(__shfl(z, k + 3), Ws[(k + 3) * 64 + lane], o3);
        }
        float o = fmaxf((o0 + o1) + (o2 + o3), 0.0f);
        hout[(size_t)i * 64 + lane] = __float2bfloat16(o);
        if (DO_POOL) {
            int g = n2g[i];
            if (g != curg) {
                if (curg >= 0) atomicAdd(&sums[(size_t)curg * 64 + lane], pacc);
                curg = g;
                pacc = 0.0f;
            }
            pacc += o;
        }
    }
    if (DO_POOL && curg >= 0) atomicAdd(&sums[(size_t)curg * 64 + lane], pacc);
}

// out[g] = sigmoid(relu(mean_h @ Ws1 + bs1) @ Ws2 + bs2)
__global__ __launch_bounds__(64) void scorer_kernel(
        const float* __restrict__ sums, const float* __restrict__ cnts,
        const float* __restrict__ Ws1, const float* __restrict__ bs1,
        const float* __restrict__ Ws2, const float* __restrict__ bs2,
        float* __restrict__ out) {
    int g = blockIdx.x, j = threadIdx.x;
    __shared__ float hgs[64];
    float c = cnts[g];
    hgs[j] = sums[(size_t)g * 64 + j] / fmaxf(c, 1.0f);
    __syncthreads();
    float acc = bs1[j];
    #pragma unroll
    for (int k = 0; k < 64; ++k)
        acc = fmaf(hgs[k], Ws1[k * 64 + j], acc);
    float z = fmaxf(acc, 0.0f) * Ws2[j];
    #pragma unroll
    for (int off = 32; off > 0; off >>= 1) z += __shfl_xor(z, off);
    if (j == 0) out[g] = 1.0f / (1.0f + expf(-(z + bs2[0])));
}

extern "C" void kernel_launch(void* const* d_in, const int* in_sizes, int n_in,
                              void* d_out, int out_size, void* d_ws, size_t ws_size,
                              hipStream_t stream) {
    const void*  u_flag = d_in[0];
    const void*  v_flag = d_in[1];
    const int*   src    = (const int*)d_in[2];
    const int*   dst    = (const int*)d_in[3];
    const int*   n2g    = (const int*)d_in[4];
    const float* W0     = (const float*)d_in[5];
    const float* b0     = (const float*)d_in[6];
    const float* eps0   = (const float*)d_in[7];
    const float* W1     = (const float*)d_in[8];
    const float* b1     = (const float*)d_in[9];
    const float* eps1   = (const float*)d_in[10];
    const float* W2     = (const float*)d_in[11];
    const float* b2     = (const float*)d_in[12];
    const float* eps2   = (const float*)d_in[13];
    const float* Ws1    = (const float*)d_in[14];
    const float* bs1    = (const float*)d_in[15];
    const float* Ws2    = (const float*)d_in[16];
    const float* bs2    = (const float*)d_in[17];
    float* out = (float*)d_out;

    // ---- workspace layout (int = 4-byte units), NON-OVERLAPPING ----
    // h_a / h_b are NN*64 bf16 = 6.4M elems * 2B = 12.8 MB = 3,200,000 ints EACH.
    int*    ws     = (int*)d_ws;
    int*    rowptr = ws;                                    // [0,       100001)
    int*    cursor = ws + 100004;                           // [100004,  200004)
    int*    bsum   = ws + 200004;                           // [200004,  200132)
    int*    flag   = ws + 200132;                           // [200132,  200136)
    float2* feat   = (float2*)(ws + 200136);                // [200136,  400136)  NN float2
    __hip_bfloat16* h_a = (__hip_bfloat16*)(ws + 400136);   // [400136,  3600136)
    __hip_bfloat16* h_b = (__hip_bfloat16*)(ws + 3600136);  // [3600136, 6800136)
    int*    esrc   = ws + 6800136;                          // [6800136, 7800136)
    float*  sums   = (float*)(ws + 7800136);                // [7800136, 7865672)
    float*  cnts   = (float*)(ws + 7865672);                // [7865672, 7866696)

    const int B256 = 256;
    const int nb1 = (NN + SCAN_B - 1) / SCAN_B;             // 98

    // feature build + counts
    detect_bool_kernel<<<1, 256, 0, stream>>>((const unsigned char*)u_flag, NN, flag);
    feat_kernel<<<(NN + B256 - 1) / B256, B256, 0, stream>>>(u_flag, v_flag, flag, feat, NN);
    hipMemsetAsync(sums, 0, ((size_t)NB * 64 + NB) * sizeof(float), stream);
    cnt_kernel<<<(NN + B256 - 1) / B256, B256, 0, stream>>>(n2g, cnts, NN);

    // CSR build: deg -> exclusive scan -> scatter by cursor
    hipMemsetAsync(rowptr, 0, (size_t)(NN + 1) * sizeof(int), stream);
    hist_kernel<<<(NE + B256 - 1) / B256, B256, 0, stream>>>(dst, rowptr, NE);
    scan1_kernel<<<nb1, SCAN_B, 0, stream>>>(rowptr, bsum, NN);
    scan2_kernel<<<1, 128, 0, stream>>>(bsum, nb1);
    scan3_kernel<<<(NN + 1 + SCAN_B - 1) / SCAN_B, SCAN_B, 0, stream>>>(rowptr, bsum, cursor, NN, NE);
    scatter_kernel<<<(NE + B256 - 1) / B256, B256, 0, stream>>>(src, dst, cursor, esrc, NE);

    // fused GIN layers (2048 blocks -> 8 blocks/CU -> 32 waves/CU)
    gin_layer0_kernel<<<2048, 256, 0, stream>>>(rowptr, esrc, feat, W0, b0, eps0, h_a);
    gin_layer_kernel<0><<<2048, 256, 0, stream>>>(rowptr, esrc, h_a, W1, b1, eps1, h_b,
                                                  n2g, sums);
    gin_layer_kernel<1><<<2048, 256, 0, stream>>>(rowptr, esrc, h_b, W2, b2, eps2, h_a,
                                                  n2g, sums);

    // scorer
    scorer_kernel<<<NB, 64, 0, stream>>>(sums, cnts, Ws1, bs1, Ws2, bs2, out);
}

// Round 6
// 424.641 us; speedup vs baseline: 1.9057x; 1.0553x over previous
//
#include <hip/hip_runtime.h>
#include <hip/hip_bf16.h>
#include <math.h>

#define NN 100000      // nodes
#define NE 1000000     // edges
#define NB 1024        // graphs
#define SCAN_B 1024

// ---------------------------------------------------------------------------
// Detect whether the bool inputs were pushed as 1-byte bools or int32.
__global__ void detect_bool_kernel(const unsigned char* __restrict__ p,
                                   int nbytes, int* __restrict__ flag) {
    __shared__ int cnt_s[256];
    int c = 0;
    for (int i = threadIdx.x; i < nbytes; i += 256) c += (p[i] != 0);
    cnt_s[threadIdx.x] = c;
    __syncthreads();
    for (int s = 128; s > 0; s >>= 1) {
        if (threadIdx.x < s) cnt_s[threadIdx.x] += cnt_s[threadIdx.x + s];
        __syncthreads();
    }
    if (threadIdx.x == 0) flag[0] = (cnt_s[0] * 4 > nbytes) ? 1 : 0;
}

__global__ void feat_kernel(const void* __restrict__ u, const void* __restrict__ v,
                            const int* __restrict__ flag, float2* __restrict__ feat,
                            int n) {
    int i = blockIdx.x * blockDim.x + threadIdx.x;
    if (i >= n) return;
    float fu, fv;
    if (flag[0]) {
        fu = ((const unsigned char*)u)[i] ? 1.0f : 0.0f;
        fv = ((const unsigned char*)v)[i] ? 1.0f : 0.0f;
    } else {
        fu = ((const int*)u)[i] ? 1.0f : 0.0f;
        fv = ((const int*)v)[i] ? 1.0f : 0.0f;
    }
    feat[i] = make_float2(fu, fv);
}

// ---------------- CSR build (per call) -----------------
__global__ void hist_kernel(const int* __restrict__ dst, int* __restrict__ deg, int e) {
    int i = blockIdx.x * blockDim.x + threadIdx.x;
    if (i < e) atomicAdd(&deg[dst[i]], 1);
}

__global__ void scan1_kernel(int* __restrict__ data, int* __restrict__ bsum, int n) {
    __shared__ int s[SCAN_B];
    int tid = threadIdx.x, gid = blockIdx.x * SCAN_B + tid;
    int v = (gid < n) ? data[gid] : 0;
    s[tid] = v;
    __syncthreads();
    for (int off = 1; off < SCAN_B; off <<= 1) {
        int t = (tid >= off) ? s[tid - off] : 0;
        __syncthreads();
        s[tid] += t;
        __syncthreads();
    }
    if (gid < n) data[gid] = s[tid] - v;           // exclusive (pre-offset)
    if (tid == SCAN_B - 1) bsum[blockIdx.x] = s[tid];
}

__global__ void scan2_kernel(int* __restrict__ bsum, int nb) {
    __shared__ int s[128];
    int tid = threadIdx.x;
    int v = (tid < nb) ? bsum[tid] : 0;
    s[tid] = v;
    __syncthreads();
    for (int off = 1; off < 128; off <<= 1) {
        int t = (tid >= off) ? s[tid - off] : 0;
        __syncthreads();
        s[tid] += t;
        __syncthreads();
    }
    if (tid < nb) bsum[tid] = s[tid] - v;          // exclusive block offsets
}

__global__ void scan3_kernel(int* __restrict__ data, const int* __restrict__ bsum,
                             int* __restrict__ cursor, int n, int total) {
    int gid = blockIdx.x * SCAN_B + threadIdx.x;
    if (gid < n) {
        int r = data[gid] + bsum[gid >> 10];
        data[gid] = r;
        cursor[gid] = r;
    }
    if (gid == n) data[n] = total;
}

__global__ void scatter_kernel(const int* __restrict__ src, const int* __restrict__ dst,
                               int* __restrict__ cursor, int* __restrict__ esrc, int e) {
    int i = blockIdx.x * blockDim.x + threadIdx.x;
    if (i < e) {
        int pos = atomicAdd(&cursor[dst[i]], 1);
        esrc[pos] = src[i];
    }
}

__global__ void cnt_kernel(const int* __restrict__ n2g, float* __restrict__ cnts, int n) {
    int i = blockIdx.x * blockDim.x + threadIdx.x;
    if (i < n) atomicAdd(&cnts[n2g[i]], 1.0f);
}

// ---------------- layer 0 (dim 2): atomic scatter + elementwise node ------
// sums of 0/1 floats are exact integers < 2^24 -> deterministic.
__global__ void edge0_kernel(const int* __restrict__ src, const int* __restrict__ dst,
                             const float2* __restrict__ feat, float* __restrict__ agg0,
                             int e) {
    int i = blockIdx.x * blockDim.x + threadIdx.x;
    if (i >= e) return;
    int s = src[i], d = dst[i];
    float2 f = feat[s];
    if (f.x != 0.0f) atomicAdd(&agg0[2 * d],     f.x);
    if (f.y != 0.0f) atomicAdd(&agg0[2 * d + 1], f.y);
}

__global__ void node0_kernel(const float2* __restrict__ feat, const float* __restrict__ agg0,
                             const float* __restrict__ W0, const float* __restrict__ b0,
                             const float* __restrict__ epsp, __hip_bfloat16* __restrict__ hout,
                             int n) {
    int idx = blockIdx.x * blockDim.x + threadIdx.x;
    int i = idx >> 6, j = idx & 63;
    if (i >= n) return;
    float e = 1.0f + epsp[0];
    float2 f = feat[i];
    float z0 = fmaf(e, f.x, agg0[2 * i]);
    float z1 = fmaf(e, f.y, agg0[2 * i + 1]);
    float acc = fmaf(z0, W0[j], fmaf(z1, W0[64 + j], b0[j]));
    hout[idx] = __float2bfloat16(fmaxf(acc, 0.0f));
}

// ---------------- layers 1/2: packed gather (8 edges/load) + reg GEMV ------
static __device__ __forceinline__ float bf_lo(unsigned int u) {
    return __uint_as_float(u << 16);
}
static __device__ __forceinline__ float bf_hi(unsigned int u) {
    return __uint_as_float(u & 0xffff0000u);
}

template <int DO_POOL>
__global__ __launch_bounds__(256) void gin_layer_kernel(
        const int* __restrict__ rowptr, const int* __restrict__ esrc,
        const __hip_bfloat16* __restrict__ hin,
        const float* __restrict__ W, const float* __restrict__ b,
        const float* __restrict__ epsp, __hip_bfloat16* __restrict__ hout,
        const int* __restrict__ n2g, float* __restrict__ sums) {
    const int tid = threadIdx.x;
    const int lane = tid & 63;
    const int g = lane >> 3;       // edge-group 0..7
    const int sub = lane & 7;      // 16B chunk within row (cols 8*sub..8*sub+7)
    // W in registers: Wreg[k] = W[k][lane]
    float Wreg[64];
    #pragma unroll
    for (int k = 0; k < 64; ++k) Wreg[k] = W[k * 64 + lane];
    const float ep = 1.0f + epsp[0];
    const float bj = b[lane];
    const int wid = (blockIdx.x * blockDim.x + tid) >> 6;
    const int nwaves = (gridDim.x * blockDim.x) >> 6;
    const int per = (NN + nwaves - 1) / nwaves;
    int i0 = wid * per, i1 = min(NN, i0 + per);
    float pacc = 0.0f;
    int curg = -1;
    for (int i = i0; i < i1; ++i) {
        int e0 = rowptr[i], eE = rowptr[i + 1];
        // own row (issue early; consumed after combine)
        const uint4* own_p = (const uint4*)(hin + (size_t)i * 64);
        uint4 ov = own_p[sub];
        float acc[8];
        #pragma unroll
        for (int c = 0; c < 8; ++c) acc[c] = 0.0f;
        for (int ec = e0; ec < eE; ec += 64) {
            int nc = min(eE - ec, 64);
            int sidx = (ec + lane < eE) ? esrc[ec + lane] : 0;
            for (int k = 0; k < nc; k += 8) {
                int et = k + g;
                int s = __shfl(sidx, et);               // group g's source row
                float m = (et < nc) ? 1.0f : 0.0f;
                const uint4* rp = (const uint4*)(hin + (size_t)s * 64);
                uint4 v = rp[sub];                      // 8 rows per wave-load
                acc[0] = fmaf(m, bf_lo(v.x), acc[0]);
                acc[1] = fmaf(m, bf_hi(v.x), acc[1]);
                acc[2] = fmaf(m, bf_lo(v.y), acc[2]);
                acc[3] = fmaf(m, bf_hi(v.y), acc[3]);
                acc[4] = fmaf(m, bf_lo(v.z), acc[4]);
                acc[5] = fmaf(m, bf_hi(v.z), acc[5]);
                acc[6] = fmaf(m, bf_lo(v.w), acc[6]);
                acc[7] = fmaf(m, bf_hi(v.w), acc[7]);
            }
        }
        // fold the 8 edge-groups (lane bits 3,4,5)
        #pragma unroll
        for (int off = 8; off < 64; off <<= 1) {
            #pragma unroll
            for (int c = 0; c < 8; ++c) acc[c] += __shfl_xor(acc[c], off);
        }
        // add (1+eps)*own row (every lane holds its sub's cols)
        acc[0] = fmaf(ep, bf_lo(ov.x), acc[0]);
        acc[1] = fmaf(ep, bf_hi(ov.x), acc[1]);
        acc[2] = fmaf(ep, bf_lo(ov.y), acc[2]);
        acc[3] = fmaf(ep, bf_hi(ov.y), acc[3]);
        acc[4] = fmaf(ep, bf_lo(ov.z), acc[4]);
        acc[5] = fmaf(ep, bf_hi(ov.z), acc[5]);
        acc[6] = fmaf(ep, bf_lo(ov.w), acc[6]);
        acc[7] = fmaf(ep, bf_hi(ov.w), acc[7]);
        // GEMV: o_j = b_j + sum_k z_k * W[k][j]; z_k = acc[k&7] @ lane k>>3
        float o0 = bj, o1 = 0.0f, o2 = 0.0f, o3 = 0.0f;
        #pragma unroll
        for (int k = 0; k < 64; k += 4) {
            float z0 = __int_as_float(__builtin_amdgcn_readlane(__float_as_int(acc[(k    ) & 7]), (k    ) >> 3));
            float z1 = __int_as_float(__builtin_amdgcn_readlane(__float_as_int(acc[(k + 1) & 7]), (k + 1) >> 3));
            float z2 = __int_as_float(__builtin_amdgcn_readlane(__float_as_int(acc[(k + 2) & 7]), (k + 2) >> 3));
            float z3 = __int_as_float(__builtin_amdgcn_readlane(__float_as_int(acc[(k + 3) & 7]), (k + 3) >> 3));
            o0 = fmaf(z0, Wreg[k],     o0);
            o1 = fmaf(z1, Wreg[k + 1], o1);
            o2 = fmaf(z2, Wreg[k + 2], o2);
            o3 = fmaf(z3, Wreg[k + 3], o3);
        }
        float o = fmaxf((o0 + o1) + (o2 + o3), 0.0f);
        hout[(size_t)i * 64 + lane] = __float2bfloat16(o);
        if (DO_POOL) {
            int gg = n2g[i];
            if (gg != curg) {
                if (curg >= 0) atomicAdd(&sums[(size_t)curg * 64 + lane], pacc);
                curg = gg;
                pacc = 0.0f;
            }
            pacc += o;
        }
    }
    if (DO_POOL && curg >= 0) atomicAdd(&sums[(size_t)curg * 64 + lane], pacc);
}

// out[g] = sigmoid(relu(mean_h @ Ws1 + bs1) @ Ws2 + bs2)
__global__ __launch_bounds__(64) void scorer_kernel(
        const float* __restrict__ sums, const float* __restrict__ cnts,
        const float* __restrict__ Ws1, const float* __restrict__ bs1,
        const float* __restrict__ Ws2, const float* __restrict__ bs2,
        float* __restrict__ out) {
    int g = blockIdx.x, j = threadIdx.x;
    __shared__ float hgs[64];
    float c = cnts[g];
    hgs[j] = sums[(size_t)g * 64 + j] / fmaxf(c, 1.0f);
    __syncthreads();
    float acc = bs1[j];
    #pragma unroll
    for (int k = 0; k < 64; ++k)
        acc = fmaf(hgs[k], Ws1[k * 64 + j], acc);
    float z = fmaxf(acc, 0.0f) * Ws2[j];
    #pragma unroll
    for (int off = 32; off > 0; off >>= 1) z += __shfl_xor(z, off);
    if (j == 0) out[g] = 1.0f / (1.0f + expf(-(z + bs2[0])));
}

extern "C" void kernel_launch(void* const* d_in, const int* in_sizes, int n_in,
                              void* d_out, int out_size, void* d_ws, size_t ws_size,
                              hipStream_t stream) {
    const void*  u_flag = d_in[0];
    const void*  v_flag = d_in[1];
    const int*   src    = (const int*)d_in[2];
    const int*   dst    = (const int*)d_in[3];
    const int*   n2g    = (const int*)d_in[4];
    const float* W0     = (const float*)d_in[5];
    const float* b0     = (const float*)d_in[6];
    const float* eps0   = (const float*)d_in[7];
    const float* W1     = (const float*)d_in[8];
    const float* b1     = (const float*)d_in[9];
    const float* eps1   = (const float*)d_in[10];
    const float* W2     = (const float*)d_in[11];
    const float* b2     = (const float*)d_in[12];
    const float* eps2   = (const float*)d_in[13];
    const float* Ws1    = (const float*)d_in[14];
    const float* bs1    = (const float*)d_in[15];
    const float* Ws2    = (const float*)d_in[16];
    const float* bs2    = (const float*)d_in[17];
    float* out = (float*)d_out;

    // ---- workspace layout (int = 4-byte units), NON-OVERLAPPING ----
    int*    ws     = (int*)d_ws;
    int*    rowptr = ws;                                    // [0,       100001)
    int*    cursor = ws + 100004;                           // [100004,  200004)
    int*    bsum   = ws + 200004;                           // [200004,  200132)
    int*    flag   = ws + 200132;                           // [200132,  200136)
    float2* feat   = (float2*)(ws + 200136);                // [200136,  400136)
    __hip_bfloat16* h_a = (__hip_bfloat16*)(ws + 400136);   // [400136,  3600136)
    __hip_bfloat16* h_b = (__hip_bfloat16*)(ws + 3600136);  // [3600136, 6800136)
    int*    esrc   = ws + 6800136;                          // [6800136, 7800136)
    float*  sums   = (float*)(ws + 7800136);                // [7800136, 7865672)
    float*  cnts   = (float*)(ws + 7865672);                // [7865672, 7866696)
    float*  agg0   = (float*)(ws + 7866696);                // [7866696, 8066696) NN*2

    const int B256 = 256;
    const int nb1 = (NN + SCAN_B - 1) / SCAN_B;             // 98

    // feature build + counts
    detect_bool_kernel<<<1, 256, 0, stream>>>((const unsigned char*)u_flag, NN, flag);
    feat_kernel<<<(NN + B256 - 1) / B256, B256, 0, stream>>>(u_flag, v_flag, flag, feat, NN);
    hipMemsetAsync(sums, 0, ((size_t)NB * 64 + NB) * sizeof(float), stream);
    cnt_kernel<<<(NN + B256 - 1) / B256, B256, 0, stream>>>(n2g, cnts, NN);

    // CSR build: deg -> exclusive scan -> scatter by cursor
    hipMemsetAsync(rowptr, 0, (size_t)(NN + 1) * sizeof(int), stream);
    hist_kernel<<<(NE + B256 - 1) / B256, B256, 0, stream>>>(dst, rowptr, NE);
    scan1_kernel<<<nb1, SCAN_B, 0, stream>>>(rowptr, bsum, NN);
    scan2_kernel<<<1, 128, 0, stream>>>(bsum, nb1);
    scan3_kernel<<<(NN + 1 + SCAN_B - 1) / SCAN_B, SCAN_B, 0, stream>>>(rowptr, bsum, cursor, NN, NE);
    scatter_kernel<<<(NE + B256 - 1) / B256, B256, 0, stream>>>(src, dst, cursor, esrc, NE);

    // layer 0 (atomic scatter path; exact in fp32)
    hipMemsetAsync(agg0, 0, (size_t)NN * 2 * sizeof(float), stream);
    edge0_kernel<<<(NE + B256 - 1) / B256, B256, 0, stream>>>(src, dst, feat, agg0, NE);
    node0_kernel<<<(NN * 64 + B256 - 1) / B256, B256, 0, stream>>>(feat, agg0, W0, b0, eps0, h_a, NN);

    // layers 1/2
    gin_layer_kernel<0><<<2048, 256, 0, stream>>>(rowptr, esrc, h_a, W1, b1, eps1, h_b,
                                                  n2g, sums);
    gin_layer_kernel<1><<<2048, 256, 0, stream>>>(rowptr, esrc, h_b, W2, b2, eps2, h_a,
                                                  n2g, sums);

    // scorer
    scorer_kernel<<<NB, 64, 0, stream>>>(sums, cnts, Ws1, bs1, Ws2, bs2, out);
}

// Round 7
// 423.849 us; speedup vs baseline: 1.9093x; 1.0019x over previous
//
#include <hip/hip_runtime.h>
#include <hip/hip_bf16.h>
#include <math.h>

#define NN 100000      // nodes
#define NE 1000000     // edges
#define NB 1024        // graphs
#define SCAN_B 1024

// ---------------------------------------------------------------------------
// Count nonzero bytes in the first n bytes (to detect uint8-bool vs int32
// input layout). 256 blocks, wave-reduced, one atomic per wave.
__global__ void count_kernel(const unsigned char* __restrict__ p, int n,
                             unsigned int* __restrict__ cnt) {
    int c = 0;
    for (int i = blockIdx.x * blockDim.x + threadIdx.x; i < n;
         i += gridDim.x * blockDim.x)
        c += (p[i] != 0);
    #pragma unroll
    for (int off = 32; off > 0; off >>= 1) c += __shfl_xor(c, off);
    if ((threadIdx.x & 63) == 0) atomicAdd(cnt, (unsigned int)c);
}

// feat[i] = [u, v] as float. uint8 layout iff ~50% of bytes nonzero
// (int32 0/1 little-endian -> only ~12.5% of bytes nonzero).
__global__ void feat_kernel(const void* __restrict__ u, const void* __restrict__ v,
                            const unsigned int* __restrict__ cnt,
                            float2* __restrict__ feat, int n) {
    int i = blockIdx.x * blockDim.x + threadIdx.x;
    if (i >= n) return;
    bool is_u8 = (4u * cnt[0] > (unsigned int)n);
    float fu, fv;
    if (is_u8) {
        fu = ((const unsigned char*)u)[i] ? 1.0f : 0.0f;
        fv = ((const unsigned char*)v)[i] ? 1.0f : 0.0f;
    } else {
        fu = ((const int*)u)[i] ? 1.0f : 0.0f;
        fv = ((const int*)v)[i] ? 1.0f : 0.0f;
    }
    feat[i] = make_float2(fu, fv);
}

// ---------------- CSR build (per call) -----------------
__global__ void hist_kernel(const int* __restrict__ dst, int* __restrict__ deg, int e) {
    int i = blockIdx.x * blockDim.x + threadIdx.x;
    if (i < e) atomicAdd(&deg[dst[i]], 1);
}

__global__ void scan1_kernel(int* __restrict__ data, int* __restrict__ bsum, int n) {
    __shared__ int s[SCAN_B];
    int tid = threadIdx.x, gid = blockIdx.x * SCAN_B + tid;
    int v = (gid < n) ? data[gid] : 0;
    s[tid] = v;
    __syncthreads();
    for (int off = 1; off < SCAN_B; off <<= 1) {
        int t = (tid >= off) ? s[tid - off] : 0;
        __syncthreads();
        s[tid] += t;
        __syncthreads();
    }
    if (gid < n) data[gid] = s[tid] - v;           // exclusive (pre-offset)
    if (tid == SCAN_B - 1) bsum[blockIdx.x] = s[tid];
}

__global__ void scan2_kernel(int* __restrict__ bsum, int nb) {
    __shared__ int s[128];
    int tid = threadIdx.x;
    int v = (tid < nb) ? bsum[tid] : 0;
    s[tid] = v;
    __syncthreads();
    for (int off = 1; off < 128; off <<= 1) {
        int t = (tid >= off) ? s[tid - off] : 0;
        __syncthreads();
        s[tid] += t;
        __syncthreads();
    }
    if (tid < nb) bsum[tid] = s[tid] - v;          // exclusive block offsets
}

__global__ void scan3_kernel(int* __restrict__ data, const int* __restrict__ bsum,
                             int* __restrict__ cursor, int n, int total) {
    int gid = blockIdx.x * SCAN_B + threadIdx.x;
    if (gid < n) {
        int r = data[gid] + bsum[gid >> 10];
        data[gid] = r;
        cursor[gid] = r;
    }
    if (gid == n) data[n] = total;
}

__global__ void scatter_kernel(const int* __restrict__ src, const int* __restrict__ dst,
                               int* __restrict__ cursor, int* __restrict__ esrc, int e) {
    int i = blockIdx.x * blockDim.x + threadIdx.x;
    if (i < e) {
        int pos = atomicAdd(&cursor[dst[i]], 1);
        esrc[pos] = src[i];
    }
}

__global__ void cnt_kernel(const int* __restrict__ n2g, float* __restrict__ cnts, int n) {
    int i = blockIdx.x * blockDim.x + threadIdx.x;
    if (i < n) atomicAdd(&cnts[n2g[i]], 1.0f);
}

// ---------------- layer 0 (dim 2): atomic scatter + elementwise node ------
__global__ void edge0_kernel(const int* __restrict__ src, const int* __restrict__ dst,
                             const float2* __restrict__ feat, float* __restrict__ agg0,
                             int e) {
    int i = blockIdx.x * blockDim.x + threadIdx.x;
    if (i >= e) return;
    int s = src[i], d = dst[i];
    float2 f = feat[s];
    if (f.x != 0.0f) atomicAdd(&agg0[2 * d],     f.x);
    if (f.y != 0.0f) atomicAdd(&agg0[2 * d + 1], f.y);
}

__global__ void node0_kernel(const float2* __restrict__ feat, const float* __restrict__ agg0,
                             const float* __restrict__ W0, const float* __restrict__ b0,
                             const float* __restrict__ epsp, __hip_bfloat16* __restrict__ hout,
                             int n) {
    int idx = blockIdx.x * blockDim.x + threadIdx.x;
    int i = idx >> 6, j = idx & 63;
    if (i >= n) return;
    float e = 1.0f + epsp[0];
    float2 f = feat[i];
    float z0 = fmaf(e, f.x, agg0[2 * i]);
    float z1 = fmaf(e, f.y, agg0[2 * i + 1]);
    float acc = fmaf(z0, W0[j], fmaf(z1, W0[64 + j], b0[j]));
    hout[idx] = __float2bfloat16(fmaxf(acc, 0.0f));
}

// ---------------- layers 1/2: packed gather + LDS-W GEMV ------------------
static __device__ __forceinline__ float bf_lo(unsigned int u) {
    return __uint_as_float(u << 16);
}
static __device__ __forceinline__ float bf_hi(unsigned int u) {
    return __uint_as_float(u & 0xffff0000u);
}

template <int DO_POOL>
__global__ __launch_bounds__(256) void gin_layer_kernel(
        const int* __restrict__ rowptr, const int* __restrict__ esrc,
        const __hip_bfloat16* __restrict__ hin,
        const float* __restrict__ W, const float* __restrict__ b,
        const float* __restrict__ epsp, __hip_bfloat16* __restrict__ hout,
        const int* __restrict__ n2g, float* __restrict__ sums) {
    __shared__ float Ws[64 * 64];       // W row-major; read Ws[k*64+lane]: bank=lane%32, free
    const int tid = threadIdx.x;
    const int lane = tid & 63;
    const int g = lane >> 3;            // edge-slot group 0..7
    const int sub = lane & 7;           // 16B chunk within row (cols 8*sub..8*sub+7)
    for (int k = tid; k < 64 * 64; k += 256) Ws[k] = W[k];
    __syncthreads();
    const float ep = 1.0f + epsp[0];
    const float bj = b[lane];
    const int wid = (blockIdx.x * blockDim.x + tid) >> 6;
    const int nwaves = (gridDim.x * blockDim.x) >> 6;
    const int per = (NN + nwaves - 1) / nwaves;
    int i0 = wid * per, i1 = min(NN, i0 + per);
    float pacc = 0.0f;
    int curg = -1;
    for (int i = i0; i < i1; ++i) {
        int e0 = rowptr[i], eE = rowptr[i + 1];
        const uint4* own_p = (const uint4*)(hin + (size_t)i * 64);
        uint4 ov = own_p[sub];          // own row, issued early
        float acc[8];
        #pragma unroll
        for (int c = 0; c < 8; ++c) acc[c] = 0.0f;
        for (int ec = e0; ec < eE; ec += 64) {
            int nc = min(eE - ec, 64);  // wave-uniform
            int sidx = (ec + lane < eE) ? esrc[ec + lane] : 0;
            // 4-deep unconditional masked loads (slots base..base+3)*8+g.
            // Masked slots read row 0 (stays cache-hot).
            #define GATHER4(BASE)                                               \
            {                                                                   \
                int s_[4]; float m_[4]; uint4 v_[4];                            \
                _Pragma("unroll")                                               \
                for (int kk = 0; kk < 4; ++kk) {                                \
                    int et = (BASE + kk) * 8 + g;                               \
                    s_[kk] = __shfl(sidx, et);                                  \
                    m_[kk] = (et < nc) ? 1.0f : 0.0f;                           \
                }                                                               \
                _Pragma("unroll")                                               \
                for (int kk = 0; kk < 4; ++kk)                                  \
                    v_[kk] = *(const uint4*)(hin + (size_t)s_[kk] * 64 + sub * 8); \
                _Pragma("unroll")                                               \
                for (int kk = 0; kk < 4; ++kk) {                                \
                    acc[0] = fmaf(m_[kk], bf_lo(v_[kk].x), acc[0]);             \
                    acc[1] = fmaf(m_[kk], bf_hi(v_[kk].x), acc[1]);             \
                    acc[2] = fmaf(m_[kk], bf_lo(v_[kk].y), acc[2]);             \
                    acc[3] = fmaf(m_[kk], bf_hi(v_[kk].y), acc[3]);             \
                    acc[4] = fmaf(m_[kk], bf_lo(v_[kk].z), acc[4]);             \
                    acc[5] = fmaf(m_[kk], bf_hi(v_[kk].z), acc[5]);             \
                    acc[6] = fmaf(m_[kk], bf_lo(v_[kk].w), acc[6]);             \
                    acc[7] = fmaf(m_[kk], bf_hi(v_[kk].w), acc[7]);             \
                }                                                               \
            }
            GATHER4(0);
            if (nc > 32) GATHER4(4);
            #undef GATHER4
        }
        // fold the 8 edge-groups (lane bits 3,4,5)
        #pragma unroll
        for (int off = 8; off < 64; off <<= 1) {
            #pragma unroll
            for (int c = 0; c < 8; ++c) acc[c] += __shfl_xor(acc[c], off);
        }
        // add (1+eps)*own row
        acc[0] = fmaf(ep, bf_lo(ov.x), acc[0]);
        acc[1] = fmaf(ep, bf_hi(ov.x), acc[1]);
        acc[2] = fmaf(ep, bf_lo(ov.y), acc[2]);
        acc[3] = fmaf(ep, bf_hi(ov.y), acc[3]);
        acc[4] = fmaf(ep, bf_lo(ov.z), acc[4]);
        acc[5] = fmaf(ep, bf_hi(ov.z), acc[5]);
        acc[6] = fmaf(ep, bf_lo(ov.w), acc[6]);
        acc[7] = fmaf(ep, bf_hi(ov.w), acc[7]);
        // GEMV: o_j = b_j + sum_k z_k * W[k][j]; z_k = acc[k&7] @ lane k>>3
        float o0 = bj, o1 = 0.0f, o2 = 0.0f, o3 = 0.0f;
        #pragma unroll
        for (int k = 0; k < 64; k += 4) {
            float z0 = __int_as_float(__builtin_amdgcn_readlane(__float_as_int(acc[(k    ) & 7]), (k    ) >> 3));
            float z1 = __int_as_float(__builtin_amdgcn_readlane(__float_as_int(acc[(k + 1) & 7]), (k + 1) >> 3));
            float z2 = __int_as_float(__builtin_amdgcn_readlane(__float_as_int(acc[(k + 2) & 7]), (k + 2) >> 3));
            float z3 = __int_as_float(__builtin_amdgcn_readlane(__float_as_int(acc[(k + 3) & 7]), (k + 3) >> 3));
            o0 = fmaf(z0, Ws[(k    ) * 64 + lane], o0);
            o1 = fmaf(z1, Ws[(k + 1) * 64 + lane], o1);
            o2 = fmaf(z2, Ws[(k + 2) * 64 + lane], o2);
            o3 = fmaf(z3, Ws[(k + 3) * 64 + lane], o3);
        }
        float o = fmaxf((o0 + o1) + (o2 + o3), 0.0f);
        hout[(size_t)i * 64 + lane] = __float2bfloat16(o);
        if (DO_POOL) {
            int gg = n2g[i];
            if (gg != curg) {
                if (curg >= 0) atomicAdd(&sums[(size_t)curg * 64 + lane], pacc);
                curg = gg;
                pacc = 0.0f;
            }
            pacc += o;
        }
    }
    if (DO_POOL && curg >= 0) atomicAdd(&sums[(size_t)curg * 64 + lane], pacc);
}

// out[g] = sigmoid(relu(mean_h @ Ws1 + bs1) @ Ws2 + bs2)
__global__ __launch_bounds__(64) void scorer_kernel(
        const float* __restrict__ sums, const float* __restrict__ cnts,
        const float* __restrict__ Ws1, const float* __restrict__ bs1,
        const float* __restrict__ Ws2, const float* __restrict__ bs2,
        float* __restrict__ out) {
    int g = blockIdx.x, j = threadIdx.x;
    __shared__ float hgs[64];
    float c = cnts[g];
    hgs[j] = sums[(size_t)g * 64 + j] / fmaxf(c, 1.0f);
    __syncthreads();
    float acc = bs1[j];
    #pragma unroll
    for (int k = 0; k < 64; ++k)
        acc = fmaf(hgs[k], Ws1[k * 64 + j], acc);
    float z = fmaxf(acc, 0.0f) * Ws2[j];
    #pragma unroll
    for (int off = 32; off > 0; off >>= 1) z += __shfl_xor(z, off);
    if (j == 0) out[g] = 1.0f / (1.0f + expf(-(z + bs2[0])));
}

extern "C" void kernel_launch(void* const* d_in, const int* in_sizes, int n_in,
                              void* d_out, int out_size, void* d_ws, size_t ws_size,
                              hipStream_t stream) {
    const void*  u_flag = d_in[0];
    const void*  v_flag = d_in[1];
    const int*   src    = (const int*)d_in[2];
    const int*   dst    = (const int*)d_in[3];
    const int*   n2g    = (const int*)d_in[4];
    const float* W0     = (const float*)d_in[5];
    const float* b0     = (const float*)d_in[6];
    const float* eps0   = (const float*)d_in[7];
    const float* W1     = (const float*)d_in[8];
    const float* b1     = (const float*)d_in[9];
    const float* eps1   = (const float*)d_in[10];
    const float* W2     = (const float*)d_in[11];
    const float* b2     = (const float*)d_in[12];
    const float* eps2   = (const float*)d_in[13];
    const float* Ws1    = (const float*)d_in[14];
    const float* bs1    = (const float*)d_in[15];
    const float* Ws2    = (const float*)d_in[16];
    const float* bs2    = (const float*)d_in[17];
    float* out = (float*)d_out;

    // ---- workspace layout (int = 4-byte units), NON-OVERLAPPING ----
    int*    ws     = (int*)d_ws;
    int*    rowptr = ws;                                    // [0,       100001)
    int*    cursor = ws + 100004;                           // [100004,  200004)
    int*    bsum   = ws + 200004;                           // [200004,  200132)
    unsigned int* ucnt = (unsigned int*)(ws + 200132);      // [200132,  200136)
    float2* feat   = (float2*)(ws + 200136);                // [200136,  400136)
    __hip_bfloat16* h_a = (__hip_bfloat16*)(ws + 400136);   // [400136,  3600136)
    __hip_bfloat16* h_b = (__hip_bfloat16*)(ws + 3600136);  // [3600136, 6800136)
    int*    esrc   = ws + 6800136;                          // [6800136, 7800136)
    float*  sums   = (float*)(ws + 7800136);                // [7800136, 7865672)
    float*  cnts   = (float*)(ws + 7865672);                // [7865672, 7866696)
    float*  agg0   = (float*)(ws + 7866696);                // [7866696, 8066696) NN*2

    const int B256 = 256;
    const int nb1 = (NN + SCAN_B - 1) / SCAN_B;             // 98

    // feature build + counts
    hipMemsetAsync(ucnt, 0, sizeof(unsigned int), stream);
    count_kernel<<<256, 256, 0, stream>>>((const unsigned char*)u_flag, NN, ucnt);
    feat_kernel<<<(NN + B256 - 1) / B256, B256, 0, stream>>>(u_flag, v_flag, ucnt, feat, NN);
    hipMemsetAsync(sums, 0, ((size_t)NB * 64 + NB) * sizeof(float), stream);
    cnt_kernel<<<(NN + B256 - 1) / B256, B256, 0, stream>>>(n2g, cnts, NN);

    // CSR build: deg -> exclusive scan -> scatter by cursor
    hipMemsetAsync(rowptr, 0, (size_t)(NN + 1) * sizeof(int), stream);
    hist_kernel<<<(NE + B256 - 1) / B256, B256, 0, stream>>>(dst, rowptr, NE);
    scan1_kernel<<<nb1, SCAN_B, 0, stream>>>(rowptr, bsum, NN);
    scan2_kernel<<<1, 128, 0, stream>>>(bsum, nb1);
    scan3_kernel<<<(NN + 1 + SCAN_B - 1) / SCAN_B, SCAN_B, 0, stream>>>(rowptr, bsum, cursor, NN, NE);
    scatter_kernel<<<(NE + B256 - 1) / B256, B256, 0, stream>>>(src, dst, cursor, esrc, NE);

    // layer 0 (atomic scatter path; exact in fp32)
    hipMemsetAsync(agg0, 0, (size_t)NN * 2 * sizeof(float), stream);
    edge0_kernel<<<(NE + B256 - 1) / B256, B256, 0, stream>>>(src, dst, feat, agg0, NE);
    node0_kernel<<<(NN * 64 + B256 - 1) / B256, B256, 0, stream>>>(feat, agg0, W0, b0, eps0, h_a, NN);

    // layers 1/2
    gin_layer_kernel<0><<<2048, 256, 0, stream>>>(rowptr, esrc, h_a, W1, b1, eps1, h_b,
                                                  n2g, sums);
    gin_layer_kernel<1><<<2048, 256, 0, stream>>>(rowptr, esrc, h_b, W2, b2, eps2, h_a,
                                                  n2g, sums);

    // scorer
    scorer_kernel<<<NB, 64, 0, stream>>>(sums, cnts, Ws1, bs1, Ws2, bs2, out);
}

// Round 8
// 300.970 us; speedup vs baseline: 2.6888x; 1.4083x over previous
//
#include <hip/hip_runtime.h>
#include <hip/hip_bf16.h>
#include <math.h>

#define NN 100000      // nodes
#define NE 1000000     // edges
#define NB 1024        // graphs
#define SCAN_B 1024
#define NCHUNK 6250    // NN/16

typedef __attribute__((ext_vector_type(8))) short short8v;
typedef __attribute__((ext_vector_type(4))) float f32x4;

union frag16 { uint4 u; short8v s; };

static __device__ __forceinline__ float bf_lo(unsigned int u) {
    return __uint_as_float(u << 16);
}
static __device__ __forceinline__ float bf_hi(unsigned int u) {
    return __uint_as_float(u & 0xffff0000u);
}
static __device__ __forceinline__ unsigned int bf16_rne(float f) {
    unsigned int u = __float_as_uint(f);
    return (u + 0x7fffu + ((u >> 16) & 1u)) >> 16;
}
static __device__ __forceinline__ unsigned int pack_bf16(float a, float b) {
    return bf16_rne(a) | (bf16_rne(b) << 16);
}

// ---------------------------------------------------------------------------
// Count nonzero bytes (uint8-bool vs int32 layout detection).
__global__ void count_kernel(const unsigned char* __restrict__ p, int n,
                             unsigned int* __restrict__ cnt) {
    int c = 0;
    for (int i = blockIdx.x * blockDim.x + threadIdx.x; i < n;
         i += gridDim.x * blockDim.x)
        c += (p[i] != 0);
    #pragma unroll
    for (int off = 32; off > 0; off >>= 1) c += __shfl_xor(c, off);
    if ((threadIdx.x & 63) == 0) atomicAdd(cnt, (unsigned int)c);
}

__global__ void feat_kernel(const void* __restrict__ u, const void* __restrict__ v,
                            const unsigned int* __restrict__ cnt,
                            float2* __restrict__ feat, int n) {
    int i = blockIdx.x * blockDim.x + threadIdx.x;
    if (i >= n) return;
    bool is_u8 = (4u * cnt[0] > (unsigned int)n);
    float fu, fv;
    if (is_u8) {
        fu = ((const unsigned char*)u)[i] ? 1.0f : 0.0f;
        fv = ((const unsigned char*)v)[i] ? 1.0f : 0.0f;
    } else {
        fu = ((const int*)u)[i] ? 1.0f : 0.0f;
        fv = ((const int*)v)[i] ? 1.0f : 0.0f;
    }
    feat[i] = make_float2(fu, fv);
}

// ---------------- CSR build (per call) -----------------
__global__ void hist_kernel(const int* __restrict__ dst, int* __restrict__ deg, int e) {
    int i = blockIdx.x * blockDim.x + threadIdx.x;
    if (i < e) atomicAdd(&deg[dst[i]], 1);
}

__global__ void scan1_kernel(int* __restrict__ data, int* __restrict__ bsum, int n) {
    __shared__ int s[SCAN_B];
    int tid = threadIdx.x, gid = blockIdx.x * SCAN_B + tid;
    int v = (gid < n) ? data[gid] : 0;
    s[tid] = v;
    __syncthreads();
    for (int off = 1; off < SCAN_B; off <<= 1) {
        int t = (tid >= off) ? s[tid - off] : 0;
        __syncthreads();
        s[tid] += t;
        __syncthreads();
    }
    if (gid < n) data[gid] = s[tid] - v;
    if (tid == SCAN_B - 1) bsum[blockIdx.x] = s[tid];
}

__global__ void scan2_kernel(int* __restrict__ bsum, int nb) {
    __shared__ int s[128];
    int tid = threadIdx.x;
    int v = (tid < nb) ? bsum[tid] : 0;
    s[tid] = v;
    __syncthreads();
    for (int off = 1; off < 128; off <<= 1) {
        int t = (tid >= off) ? s[tid - off] : 0;
        __syncthreads();
        s[tid] += t;
        __syncthreads();
    }
    if (tid < nb) bsum[tid] = s[tid] - v;
}

__global__ void scan3_kernel(int* __restrict__ data, const int* __restrict__ bsum,
                             int* __restrict__ cursor, int n, int total) {
    int gid = blockIdx.x * SCAN_B + threadIdx.x;
    if (gid < n) {
        int r = data[gid] + bsum[gid >> 10];
        data[gid] = r;
        cursor[gid] = r;
    }
    if (gid == n) data[n] = total;
}

__global__ void scatter_kernel(const int* __restrict__ src, const int* __restrict__ dst,
                               int* __restrict__ cursor, int* __restrict__ esrc, int e) {
    int i = blockIdx.x * blockDim.x + threadIdx.x;
    if (i < e) {
        int pos = atomicAdd(&cursor[dst[i]], 1);
        esrc[pos] = src[i];
    }
}

// graph start offsets from contiguous n2g
__global__ void boundary_kernel(const int* __restrict__ n2g, int* __restrict__ gstart,
                                int n) {
    int i = blockIdx.x * blockDim.x + threadIdx.x;
    if (i >= n) return;
    int g = n2g[i];
    if (i == 0) {
        gstart[g] = 0;
        gstart[NB] = n;
    } else if (n2g[i - 1] != g) {
        gstart[g] = i;
    }
}

// ---------------- layer 0 (dim 2): atomic scatter + elementwise node ------
__global__ void edge0_kernel(const int* __restrict__ src, const int* __restrict__ dst,
                             const float2* __restrict__ feat, float* __restrict__ agg0,
                             int e) {
    int i = blockIdx.x * blockDim.x + threadIdx.x;
    if (i >= e) return;
    int s = src[i], d = dst[i];
    float2 f = feat[s];
    if (f.x != 0.0f) atomicAdd(&agg0[2 * d],     f.x);
    if (f.y != 0.0f) atomicAdd(&agg0[2 * d + 1], f.y);
}

__global__ void node0_kernel(const float2* __restrict__ feat, const float* __restrict__ agg0,
                             const float* __restrict__ W0, const float* __restrict__ b0,
                             const float* __restrict__ epsp, unsigned short* __restrict__ hout,
                             int n) {
    int idx = blockIdx.x * blockDim.x + threadIdx.x;
    int i = idx >> 6, j = idx & 63;
    if (i >= n) return;
    float e = 1.0f + epsp[0];
    float2 f = feat[i];
    float z0 = fmaf(e, f.x, agg0[2 * i]);
    float z1 = fmaf(e, f.y, agg0[2 * i + 1]);
    float acc = fmaf(z0, W0[j], fmaf(z1, W0[64 + j], b0[j]));
    hout[idx] = (unsigned short)bf16_rne(fmaxf(acc, 0.0f));
}

// ---------------- layers 1/2: node-group gather + MFMA GEMV ---------------
// Wave = 16 nodes per chunk. Phase A (x2): 8 nodes in parallel (group=node),
// z packed bf16 -> per-wave LDS [16][64] with XOR chunk swizzle.
// Phase B: mfma_f32_16x16x32_bf16, W fragments preloaded in VGPRs.
__global__ __launch_bounds__(256) void gin_layer_kernel(
        const int* __restrict__ rowptr, const int* __restrict__ esrc,
        const unsigned short* __restrict__ hin,
        const float* __restrict__ W, const float* __restrict__ b,
        const float* __restrict__ epsp, unsigned short* __restrict__ hout) {
    __shared__ __align__(16) unsigned char zall[4][2048];   // per-wave z[16][64] bf16
    const int tid = threadIdx.x;
    const int lane = tid & 63;
    const int g = lane >> 3;            // node group 0..7
    const int sub = lane & 7;           // 16B chunk (cols 8*sub..8*sub+7)
    unsigned char* zw = &zall[tid >> 6][0];
    const float ep = 1.0f + epsp[0];

    // preload B fragments: Bf[n][t] holds W[k=32t+8*(lane>>4)+j][16n+(lane&15)]
    const int bcol = (lane & 15);
    const int krow = (lane >> 4) * 8;
    frag16 Bf[4][2];
    #pragma unroll
    for (int n = 0; n < 4; ++n) {
        #pragma unroll
        for (int t = 0; t < 2; ++t) {
            unsigned int p[4];
            #pragma unroll
            for (int jj = 0; jj < 4; ++jj) {
                int k0 = t * 32 + krow + 2 * jj;
                float w0 = W[(size_t)k0 * 64 + n * 16 + bcol];
                float w1 = W[(size_t)(k0 + 1) * 64 + n * 16 + bcol];
                p[jj] = pack_bf16(w0, w1);
            }
            Bf[n][t].u = make_uint4(p[0], p[1], p[2], p[3]);
        }
    }
    float bj[4];
    #pragma unroll
    for (int n = 0; n < 4; ++n) bj[n] = b[n * 16 + bcol];

    const int wid = (blockIdx.x * blockDim.x + tid) >> 6;
    const int nwaves = (gridDim.x * blockDim.x) >> 6;

    for (int chunk = wid; chunk < NCHUNK; chunk += nwaves) {
        const int cbase = chunk * 16;
        // ---- Phase A: two batches of 8 nodes ----
        #pragma unroll
        for (int b8 = 0; b8 < 2; ++b8) {
            int node = cbase + b8 * 8 + g;
            int e0 = rowptr[node], e1 = rowptr[node + 1];
            int deg = e1 - e0;
            uint4 ov = ((const uint4*)(hin + (size_t)node * 64))[sub];
            float acc[8];
            #pragma unroll
            for (int c = 0; c < 8; ++c) acc[c] = 0.0f;
            // wave-uniform max degree (folds over group bits)
            int md = deg;
            md = max(md, __shfl_xor(md, 8));
            md = max(md, __shfl_xor(md, 16));
            md = max(md, __shfl_xor(md, 32));
            #pragma unroll 2
            for (int t = 0; t < md; ++t) {
                int em = max(min(e0 + t, e1 - 1), 0);
                int sraw = esrc[em];
                bool act = (t < deg);
                int s = act ? sraw : node;          // masked: own row (L1-hot)
                uint4 v = ((const uint4*)(hin + (size_t)s * 64))[sub];
                float m = act ? 1.0f : 0.0f;
                acc[0] = fmaf(m, bf_lo(v.x), acc[0]);
                acc[1] = fmaf(m, bf_hi(v.x), acc[1]);
                acc[2] = fmaf(m, bf_lo(v.y), acc[2]);
                acc[3] = fmaf(m, bf_hi(v.y), acc[3]);
                acc[4] = fmaf(m, bf_lo(v.z), acc[4]);
                acc[5] = fmaf(m, bf_hi(v.z), acc[5]);
                acc[6] = fmaf(m, bf_lo(v.w), acc[6]);
                acc[7] = fmaf(m, bf_hi(v.w), acc[7]);
            }
            acc[0] = fmaf(ep, bf_lo(ov.x), acc[0]);
            acc[1] = fmaf(ep, bf_hi(ov.x), acc[1]);
            acc[2] = fmaf(ep, bf_lo(ov.y), acc[2]);
            acc[3] = fmaf(ep, bf_hi(ov.y), acc[3]);
            acc[4] = fmaf(ep, bf_lo(ov.z), acc[4]);
            acc[5] = fmaf(ep, bf_hi(ov.z), acc[5]);
            acc[6] = fmaf(ep, bf_lo(ov.w), acc[6]);
            acc[7] = fmaf(ep, bf_hi(ov.w), acc[7]);
            // pack & swizzled LDS write: row=b8*8+g, chunk position = sub ^ (row&7)
            uint4 pk = make_uint4(pack_bf16(acc[0], acc[1]), pack_bf16(acc[2], acc[3]),
                                  pack_bf16(acc[4], acc[5]), pack_bf16(acc[6], acc[7]));
            int row = b8 * 8 + g;
            *(uint4*)&zw[row * 128 + ((sub ^ g) << 4)] = pk;
        }
        // ---- Phase B: z[16][64] @ W[64][64] via MFMA ----
        // A frag: row = lane&15, k = (lane>>4)*8 + j (+32 for t=1)
        const int arow = lane & 15;
        const int hi = lane >> 4;
        frag16 a0, a1;
        a0.u = *(const uint4*)&zw[arow * 128 + (((hi + 0) ^ (lane & 7)) << 4)];
        a1.u = *(const uint4*)&zw[arow * 128 + (((hi + 4) ^ (lane & 7)) << 4)];
        #pragma unroll
        for (int n = 0; n < 4; ++n) {
            f32x4 c = {bj[n], bj[n], bj[n], bj[n]};
            c = __builtin_amdgcn_mfma_f32_16x16x32_bf16(a0.s, Bf[n][0].s, c, 0, 0, 0);
            c = __builtin_amdgcn_mfma_f32_16x16x32_bf16(a1.s, Bf[n][1].s, c, 0, 0, 0);
            #pragma unroll
            for (int q = 0; q < 4; ++q) {
                int r = hi * 4 + q;                  // C: col=lane&15, row=(lane>>4)*4+q
                float v = fmaxf(c[q], 0.0f);
                hout[(size_t)(cbase + r) * 64 + n * 16 + bcol] =
                    (unsigned short)bf16_rne(v);
            }
        }
    }
}

// ---------------- fused mean-pool + scorer: one wave per graph ------------
__global__ __launch_bounds__(256) void pool_scorer_kernel(
        const unsigned short* __restrict__ h, const int* __restrict__ gstart,
        const float* __restrict__ Ws1, const float* __restrict__ bs1,
        const float* __restrict__ Ws2, const float* __restrict__ bs2,
        float* __restrict__ out) {
    int g = blockIdx.x * 4 + (threadIdx.x >> 6);
    int lane = threadIdx.x & 63;
    if (g >= NB) return;
    int s0 = gstart[g], s1 = gstart[g + 1];
    float a0 = 0.0f, a1 = 0.0f, a2 = 0.0f, a3 = 0.0f;
    int i = s0;
    for (; i + 4 <= s1; i += 4) {
        a0 += __uint_as_float((unsigned int)h[(size_t)(i    ) * 64 + lane] << 16);
        a1 += __uint_as_float((unsigned int)h[(size_t)(i + 1) * 64 + lane] << 16);
        a2 += __uint_as_float((unsigned int)h[(size_t)(i + 2) * 64 + lane] << 16);
        a3 += __uint_as_float((unsigned int)h[(size_t)(i + 3) * 64 + lane] << 16);
    }
    for (; i < s1; ++i)
        a0 += __uint_as_float((unsigned int)h[(size_t)i * 64 + lane] << 16);
    float mean = ((a0 + a1) + (a2 + a3)) / fmaxf((float)(s1 - s0), 1.0f);
    // o_j = bs1_j + sum_k mean_k * Ws1[k][j]
    float o = bs1[lane];
    #pragma unroll 8
    for (int k = 0; k < 64; ++k)
        o = fmaf(__shfl(mean, k), Ws1[(size_t)k * 64 + lane], o);
    float z = fmaxf(o, 0.0f) * Ws2[lane];
    #pragma unroll
    for (int off = 32; off > 0; off >>= 1) z += __shfl_xor(z, off);
    if (lane == 0) out[g] = 1.0f / (1.0f + expf(-(z + bs2[0])));
}

extern "C" void kernel_launch(void* const* d_in, const int* in_sizes, int n_in,
                              void* d_out, int out_size, void* d_ws, size_t ws_size,
                              hipStream_t stream) {
    const void*  u_flag = d_in[0];
    const void*  v_flag = d_in[1];
    const int*   src    = (const int*)d_in[2];
    const int*   dst    = (const int*)d_in[3];
    const int*   n2g    = (const int*)d_in[4];
    const float* W0     = (const float*)d_in[5];
    const float* b0     = (const float*)d_in[6];
    const float* eps0   = (const float*)d_in[7];
    const float* W1     = (const float*)d_in[8];
    const float* b1     = (const float*)d_in[9];
    const float* eps1   = (const float*)d_in[10];
    const float* W2     = (const float*)d_in[11];
    const float* b2     = (const float*)d_in[12];
    const float* eps2   = (const float*)d_in[13];
    const float* Ws1    = (const float*)d_in[14];
    const float* bs1    = (const float*)d_in[15];
    const float* Ws2    = (const float*)d_in[16];
    const float* bs2    = (const float*)d_in[17];
    float* out = (float*)d_out;

    // ---- workspace layout (int = 4-byte units), non-overlapping ----
    int*    ws     = (int*)d_ws;
    int*    rowptr = ws;                                    // [0,       100001)
    int*    cursor = ws + 100004;                           // [100004,  200004)
    int*    bsum   = ws + 200004;                           // [200004,  200132)
    unsigned int* ucnt = (unsigned int*)(ws + 200132);      // [200132,  200133)
    int*    gstart = ws + 200136;                           // [200136,  201161)
    float2* feat   = (float2*)(ws + 201164);                // [201164,  401164)
    unsigned short* h_a = (unsigned short*)(ws + 401164);   // [401164,  3601164)
    unsigned short* h_b = (unsigned short*)(ws + 3601164);  // [3601164, 6801164)
    int*    esrc   = ws + 6801164;                          // [6801164, 7801164)
    float*  agg0   = (float*)(ws + 7801164);                // [7801164, 8001164)

    const int B256 = 256;
    const int nb1 = (NN + SCAN_B - 1) / SCAN_B;             // 98

    // feature build + graph boundaries
    hipMemsetAsync(ucnt, 0, sizeof(unsigned int), stream);
    count_kernel<<<256, 256, 0, stream>>>((const unsigned char*)u_flag, NN, ucnt);
    feat_kernel<<<(NN + B256 - 1) / B256, B256, 0, stream>>>(u_flag, v_flag, ucnt, feat, NN);
    boundary_kernel<<<(NN + B256 - 1) / B256, B256, 0, stream>>>(n2g, gstart, NN);

    // CSR build: deg -> exclusive scan -> scatter by cursor
    hipMemsetAsync(rowptr, 0, (size_t)(NN + 1) * sizeof(int), stream);
    hist_kernel<<<(NE + B256 - 1) / B256, B256, 0, stream>>>(dst, rowptr, NE);
    scan1_kernel<<<nb1, SCAN_B, 0, stream>>>(rowptr, bsum, NN);
    scan2_kernel<<<1, 128, 0, stream>>>(bsum, nb1);
    scan3_kernel<<<(NN + 1 + SCAN_B - 1) / SCAN_B, SCAN_B, 0, stream>>>(rowptr, bsum, cursor, NN, NE);
    scatter_kernel<<<(NE + B256 - 1) / B256, B256, 0, stream>>>(src, dst, cursor, esrc, NE);

    // layer 0 (atomic scatter path; exact in fp32)
    hipMemsetAsync(agg0, 0, (size_t)NN * 2 * sizeof(float), stream);
    edge0_kernel<<<(NE + B256 - 1) / B256, B256, 0, stream>>>(src, dst, feat, agg0, NE);
    node0_kernel<<<(NN * 64 + B256 - 1) / B256, B256, 0, stream>>>(feat, agg0, W0, b0, eps0, h_a, NN);

    // layers 1/2 (782 blocks = 3128 waves -> exactly 2 chunks per wave)
    gin_layer_kernel<<<782, 256, 0, stream>>>(rowptr, esrc, h_a, W1, b1, eps1, h_b);
    gin_layer_kernel<<<782, 256, 0, stream>>>(rowptr, esrc, h_b, W2, b2, eps2, h_a);

    // fused mean-pool + scorer
    pool_scorer_kernel<<<NB / 4, 256, 0, stream>>>(h_a, gstart, Ws1, bs1, Ws2, bs2, out);
}

// Round 9
// 236.901 us; speedup vs baseline: 3.4160x; 1.2704x over previous
//
#include <hip/hip_runtime.h>
#include <hip/hip_bf16.h>
#include <math.h>

#define NN 100000      // nodes
#define NE 1000000     // edges
#define NB 1024        // graphs
#define SCAN_B 1024
#define NCHUNK 6250    // NN/16
#define RANGE 12500    // NN / 8 XCD dst-ranges

typedef __attribute__((ext_vector_type(8))) short short8v;
typedef __attribute__((ext_vector_type(4))) float f32x4;

union frag16 { uint4 u; short8v s; };

static __device__ __forceinline__ float bf_lo(unsigned int u) {
    return __uint_as_float(u << 16);
}
static __device__ __forceinline__ float bf_hi(unsigned int u) {
    return __uint_as_float(u & 0xffff0000u);
}
static __device__ __forceinline__ unsigned int bf16_rne(float f) {
    unsigned int u = __float_as_uint(f);
    return (u + 0x7fffu + ((u >> 16) & 1u)) >> 16;
}
static __device__ __forceinline__ unsigned int pack_bf16(float a, float b) {
    return bf16_rne(a) | (bf16_rne(b) << 16);
}

// ---------------------------------------------------------------------------
// Count nonzero bytes (uint8-bool vs int32 layout detection).
__global__ void count_kernel(const unsigned char* __restrict__ p, int n,
                             unsigned int* __restrict__ cnt) {
    int c = 0;
    for (int i = blockIdx.x * blockDim.x + threadIdx.x; i < n;
         i += gridDim.x * blockDim.x)
        c += (p[i] != 0);
    #pragma unroll
    for (int off = 32; off > 0; off >>= 1) c += __shfl_xor(c, off);
    if ((threadIdx.x & 63) == 0) atomicAdd(cnt, (unsigned int)c);
}

// featb[i] = u | (v<<1)  (packed 2-bit features, 100 KB -> L2-resident)
__global__ void featb_kernel(const void* __restrict__ u, const void* __restrict__ v,
                             const unsigned int* __restrict__ cnt,
                             unsigned char* __restrict__ featb, int n) {
    int i = blockIdx.x * blockDim.x + threadIdx.x;
    if (i >= n) return;
    bool is_u8 = (4u * cnt[0] > (unsigned int)n);
    unsigned char fu, fv;
    if (is_u8) {
        fu = ((const unsigned char*)u)[i] ? 1 : 0;
        fv = ((const unsigned char*)v)[i] ? 1 : 0;
    } else {
        fu = ((const int*)u)[i] ? 1 : 0;
        fv = ((const int*)v)[i] ? 1 : 0;
    }
    featb[i] = fu | (fv << 1);
}

// ---------------- fused hist + feature-count (XCD range-partitioned) -------
// h64[d] accumulates: deg in bits[0:21), cnt_u in [21:42), cnt_v in [42:63).
__global__ void hist64_kernel(const int* __restrict__ src, const int* __restrict__ dst,
                              const unsigned char* __restrict__ featb,
                              unsigned long long* __restrict__ h64, int e) {
    const int range = blockIdx.x & 7;
    const int lo = range * RANGE, hi = lo + RANGE;
    const int nb = gridDim.x >> 3, bi = blockIdx.x >> 3;
    for (int i = bi * blockDim.x + threadIdx.x; i < e; i += nb * blockDim.x) {
        int d = dst[i];
        if (d >= lo && d < hi) {
            unsigned char f = featb[src[i]];
            unsigned long long inc = 1ull
                | ((unsigned long long)(f & 1) << 21)
                | ((unsigned long long)(f >> 1) << 42);
            atomicAdd(&h64[d], inc);
        }
    }
}

// ---------------- scan (rowptr from h64 degrees) ---------------------------
__global__ void scan1_kernel(const unsigned long long* __restrict__ h64,
                             int* __restrict__ rowptr, int* __restrict__ bsum, int n) {
    __shared__ int s[SCAN_B];
    int tid = threadIdx.x, gid = blockIdx.x * SCAN_B + tid;
    int v = (gid < n) ? (int)(h64[gid] & 0x1FFFFFull) : 0;
    s[tid] = v;
    __syncthreads();
    for (int off = 1; off < SCAN_B; off <<= 1) {
        int t = (tid >= off) ? s[tid - off] : 0;
        __syncthreads();
        s[tid] += t;
        __syncthreads();
    }
    if (gid < n) rowptr[gid] = s[tid] - v;         // exclusive (pre-offset)
    if (tid == SCAN_B - 1) bsum[blockIdx.x] = s[tid];
}

__global__ void scan2_kernel(int* __restrict__ bsum, int nb) {
    __shared__ int s[128];
    int tid = threadIdx.x;
    int v = (tid < nb) ? bsum[tid] : 0;
    s[tid] = v;
    __syncthreads();
    for (int off = 1; off < 128; off <<= 1) {
        int t = (tid >= off) ? s[tid - off] : 0;
        __syncthreads();
        s[tid] += t;
        __syncthreads();
    }
    if (tid < nb) bsum[tid] = s[tid] - v;
}

__global__ void scan3_kernel(int* __restrict__ rowptr, const int* __restrict__ bsum,
                             int* __restrict__ cursor, int n, int total) {
    int gid = blockIdx.x * SCAN_B + threadIdx.x;
    if (gid < n) {
        int r = rowptr[gid] + bsum[gid >> 10];
        rowptr[gid] = r;
        cursor[gid] = r;
    }
    if (gid == n) rowptr[n] = total;
}

// ---------------- scatter (XCD range-partitioned: no L2 line bouncing) -----
__global__ void scatter_kernel(const int* __restrict__ src, const int* __restrict__ dst,
                               int* __restrict__ cursor, int* __restrict__ esrc, int e) {
    const int range = blockIdx.x & 7;
    const int lo = range * RANGE, hi = lo + RANGE;
    const int nb = gridDim.x >> 3, bi = blockIdx.x >> 3;
    for (int i = bi * blockDim.x + threadIdx.x; i < e; i += nb * blockDim.x) {
        int d = dst[i];
        if (d >= lo && d < hi) {
            int pos = atomicAdd(&cursor[d], 1);
            esrc[pos] = src[i];
        }
    }
}

// graph start offsets from contiguous n2g
__global__ void boundary_kernel(const int* __restrict__ n2g, int* __restrict__ gstart,
                                int n) {
    int i = blockIdx.x * blockDim.x + threadIdx.x;
    if (i >= n) return;
    int g = n2g[i];
    if (i == 0) {
        gstart[g] = 0;
        gstart[NB] = n;
    } else if (n2g[i - 1] != g) {
        gstart[g] = i;
    }
}

// ---------------- layer 0 node transform (dim 2 -> 64) ---------------------
__global__ void node0_kernel(const unsigned char* __restrict__ featb,
                             const unsigned long long* __restrict__ h64,
                             const float* __restrict__ W0, const float* __restrict__ b0,
                             const float* __restrict__ epsp, unsigned short* __restrict__ hout,
                             int n) {
    int idx = blockIdx.x * blockDim.x + threadIdx.x;
    int i = idx >> 6, j = idx & 63;
    if (i >= n) return;
    float e = 1.0f + epsp[0];
    unsigned long long hv = h64[i];
    float cu = (float)((hv >> 21) & 0x1FFFFFull);
    float cv = (float)(hv >> 42);
    unsigned char f = featb[i];
    float z0 = fmaf(e, (float)(f & 1), cu);
    float z1 = fmaf(e, (float)(f >> 1), cv);
    float acc = fmaf(z0, W0[j], fmaf(z1, W0[64 + j], b0[j]));
    hout[idx] = (unsigned short)bf16_rne(fmaxf(acc, 0.0f));
}

// ---------------- layers 1/2: node-group gather + MFMA GEMV ---------------
__global__ __launch_bounds__(256) void gin_layer_kernel(
        const int* __restrict__ rowptr, const int* __restrict__ esrc,
        const unsigned short* __restrict__ hin,
        const float* __restrict__ W, const float* __restrict__ b,
        const float* __restrict__ epsp, unsigned short* __restrict__ hout) {
    __shared__ __align__(16) unsigned char zall[4][2048];   // per-wave z[16][64] bf16
    const int tid = threadIdx.x;
    const int lane = tid & 63;
    const int g = lane >> 3;            // node group 0..7
    const int sub = lane & 7;           // 16B chunk (cols 8*sub..8*sub+7)
    unsigned char* zw = &zall[tid >> 6][0];
    const float ep = 1.0f + epsp[0];

    // preload B fragments: Bf[n][t] holds W[k=32t+8*(lane>>4)+j][16n+(lane&15)]
    const int bcol = (lane & 15);
    const int krow = (lane >> 4) * 8;
    frag16 Bf[4][2];
    #pragma unroll
    for (int n = 0; n < 4; ++n) {
        #pragma unroll
        for (int t = 0; t < 2; ++t) {
            unsigned int p[4];
            #pragma unroll
            for (int jj = 0; jj < 4; ++jj) {
                int k0 = t * 32 + krow + 2 * jj;
                float w0 = W[(size_t)k0 * 64 + n * 16 + bcol];
                float w1 = W[(size_t)(k0 + 1) * 64 + n * 16 + bcol];
                p[jj] = pack_bf16(w0, w1);
            }
            Bf[n][t].u = make_uint4(p[0], p[1], p[2], p[3]);
        }
    }
    float bj[4];
    #pragma unroll
    for (int n = 0; n < 4; ++n) bj[n] = b[n * 16 + bcol];

    const int wid = (blockIdx.x * blockDim.x + tid) >> 6;
    const int nwaves = (gridDim.x * blockDim.x) >> 6;

    for (int chunk = wid; chunk < NCHUNK; chunk += nwaves) {
        const int cbase = chunk * 16;
        // ---- Phase A: two batches of 8 nodes ----
        #pragma unroll
        for (int b8 = 0; b8 < 2; ++b8) {
            int node = cbase + b8 * 8 + g;
            int e0 = rowptr[node], e1 = rowptr[node + 1];
            int deg = e1 - e0;
            uint4 ov = ((const uint4*)(hin + (size_t)node * 64))[sub];
            float acc[8];
            #pragma unroll
            for (int c = 0; c < 8; ++c) acc[c] = 0.0f;
            int md = deg;
            md = max(md, __shfl_xor(md, 8));
            md = max(md, __shfl_xor(md, 16));
            md = max(md, __shfl_xor(md, 32));
            #pragma unroll 2
            for (int t = 0; t < md; ++t) {
                int em = max(min(e0 + t, e1 - 1), 0);
                int sraw = esrc[em];
                bool act = (t < deg);
                int s = act ? sraw : node;          // masked: own row (L1-hot)
                uint4 v = ((const uint4*)(hin + (size_t)s * 64))[sub];
                float m = act ? 1.0f : 0.0f;
                acc[0] = fmaf(m, bf_lo(v.x), acc[0]);
                acc[1] = fmaf(m, bf_hi(v.x), acc[1]);
                acc[2] = fmaf(m, bf_lo(v.y), acc[2]);
                acc[3] = fmaf(m, bf_hi(v.y), acc[3]);
                acc[4] = fmaf(m, bf_lo(v.z), acc[4]);
                acc[5] = fmaf(m, bf_hi(v.z), acc[5]);
                acc[6] = fmaf(m, bf_lo(v.w), acc[6]);
                acc[7] = fmaf(m, bf_hi(v.w), acc[7]);
            }
            acc[0] = fmaf(ep, bf_lo(ov.x), acc[0]);
            acc[1] = fmaf(ep, bf_hi(ov.x), acc[1]);
            acc[2] = fmaf(ep, bf_lo(ov.y), acc[2]);
            acc[3] = fmaf(ep, bf_hi(ov.y), acc[3]);
            acc[4] = fmaf(ep, bf_lo(ov.z), acc[4]);
            acc[5] = fmaf(ep, bf_hi(ov.z), acc[5]);
            acc[6] = fmaf(ep, bf_lo(ov.w), acc[6]);
            acc[7] = fmaf(ep, bf_hi(ov.w), acc[7]);
            uint4 pk = make_uint4(pack_bf16(acc[0], acc[1]), pack_bf16(acc[2], acc[3]),
                                  pack_bf16(acc[4], acc[5]), pack_bf16(acc[6], acc[7]));
            int row = b8 * 8 + g;
            *(uint4*)&zw[row * 128 + ((sub ^ g) << 4)] = pk;
        }
        // ---- Phase B: z[16][64] @ W[64][64] via MFMA ----
        const int arow = lane & 15;
        const int hi = lane >> 4;
        frag16 a0, a1;
        a0.u = *(const uint4*)&zw[arow * 128 + (((hi + 0) ^ (lane & 7)) << 4)];
        a1.u = *(const uint4*)&zw[arow * 128 + (((hi + 4) ^ (lane & 7)) << 4)];
        #pragma unroll
        for (int n = 0; n < 4; ++n) {
            f32x4 c = {bj[n], bj[n], bj[n], bj[n]};
            c = __builtin_amdgcn_mfma_f32_16x16x32_bf16(a0.s, Bf[n][0].s, c, 0, 0, 0);
            c = __builtin_amdgcn_mfma_f32_16x16x32_bf16(a1.s, Bf[n][1].s, c, 0, 0, 0);
            #pragma unroll
            for (int q = 0; q < 4; ++q) {
                int r = hi * 4 + q;
                float v = fmaxf(c[q], 0.0f);
                hout[(size_t)(cbase + r) * 64 + n * 16 + bcol] =
                    (unsigned short)bf16_rne(v);
            }
        }
    }
}

// ---------------- fused mean-pool + scorer: one wave per graph ------------
__global__ __launch_bounds__(256) void pool_scorer_kernel(
        const unsigned short* __restrict__ h, const int* __restrict__ gstart,
        const float* __restrict__ Ws1, const float* __restrict__ bs1,
        const float* __restrict__ Ws2, const float* __restrict__ bs2,
        float* __restrict__ out) {
    int g = blockIdx.x * 4 + (threadIdx.x >> 6);
    int lane = threadIdx.x & 63;
    if (g >= NB) return;
    int s0 = gstart[g], s1 = gstart[g + 1];
    float a0 = 0.0f, a1 = 0.0f, a2 = 0.0f, a3 = 0.0f;
    int i = s0;
    for (; i + 4 <= s1; i += 4) {
        a0 += __uint_as_float((unsigned int)h[(size_t)(i    ) * 64 + lane] << 16);
        a1 += __uint_as_float((unsigned int)h[(size_t)(i + 1) * 64 + lane] << 16);
        a2 += __uint_as_float((unsigned int)h[(size_t)(i + 2) * 64 + lane] << 16);
        a3 += __uint_as_float((unsigned int)h[(size_t)(i + 3) * 64 + lane] << 16);
    }
    for (; i < s1; ++i)
        a0 += __uint_as_float((unsigned int)h[(size_t)i * 64 + lane] << 16);
    float mean = ((a0 + a1) + (a2 + a3)) / fmaxf((float)(s1 - s0), 1.0f);
    float o = bs1[lane];
    #pragma unroll 8
    for (int k = 0; k < 64; ++k)
        o = fmaf(__shfl(mean, k), Ws1[(size_t)k * 64 + lane], o);
    float z = fmaxf(o, 0.0f) * Ws2[lane];
    #pragma unroll
    for (int off = 32; off > 0; off >>= 1) z += __shfl_xor(z, off);
    if (lane == 0) out[g] = 1.0f / (1.0f + expf(-(z + bs2[0])));
}

extern "C" void kernel_launch(void* const* d_in, const int* in_sizes, int n_in,
                              void* d_out, int out_size, void* d_ws, size_t ws_size,
                              hipStream_t stream) {
    const void*  u_flag = d_in[0];
    const void*  v_flag = d_in[1];
    const int*   src    = (const int*)d_in[2];
    const int*   dst    = (const int*)d_in[3];
    const int*   n2g    = (const int*)d_in[4];
    const float* W0     = (const float*)d_in[5];
    const float* b0     = (const float*)d_in[6];
    const float* eps0   = (const float*)d_in[7];
    const float* W1     = (const float*)d_in[8];
    const float* b1     = (const float*)d_in[9];
    const float* eps1   = (const float*)d_in[10];
    const float* W2     = (const float*)d_in[11];
    const float* b2     = (const float*)d_in[12];
    const float* eps2   = (const float*)d_in[13];
    const float* Ws1    = (const float*)d_in[14];
    const float* bs1    = (const float*)d_in[15];
    const float* Ws2    = (const float*)d_in[16];
    const float* bs2    = (const float*)d_in[17];
    float* out = (float*)d_out;

    // ---- workspace layout (int = 4-byte units), non-overlapping ----
    int*    ws     = (int*)d_ws;
    int*    rowptr = ws;                                    // [0,       100001)
    int*    cursor = ws + 100004;                           // [100004,  200004)
    int*    bsum   = ws + 200004;                           // [200004,  200132)
    unsigned int* ucnt = (unsigned int*)(ws + 200132);      // [200132,  200133)
    int*    gstart = ws + 200136;                           // [200136,  201161)
    unsigned char* featb = (unsigned char*)(ws + 201164);   // [201164,  226164) 100000 B
    unsigned long long* h64 = (unsigned long long*)(ws + 226164); // [226164, 426164) 8B-aligned
    unsigned short* h_a = (unsigned short*)(ws + 426164);   // [426164,  3626164)
    unsigned short* h_b = (unsigned short*)(ws + 3626164);  // [3626164, 6826164)
    int*    esrc   = ws + 6826164;                          // [6826164, 7826164)

    const int B256 = 256;
    const int nb1 = (NN + SCAN_B - 1) / SCAN_B;             // 98

    // feature build + graph boundaries
    hipMemsetAsync(ucnt, 0, sizeof(unsigned int), stream);
    hipMemsetAsync(h64, 0, (size_t)NN * sizeof(unsigned long long), stream);
    count_kernel<<<256, 256, 0, stream>>>((const unsigned char*)u_flag, NN, ucnt);
    featb_kernel<<<(NN + B256 - 1) / B256, B256, 0, stream>>>(u_flag, v_flag, ucnt, featb, NN);
    boundary_kernel<<<(NN + B256 - 1) / B256, B256, 0, stream>>>(n2g, gstart, NN);

    // fused hist + layer-0 aggregation (XCD range-partitioned 64-bit atomics)
    hist64_kernel<<<2048, B256, 0, stream>>>(src, dst, featb, h64, NE);

    // scan -> rowptr/cursor
    scan1_kernel<<<nb1, SCAN_B, 0, stream>>>(h64, rowptr, bsum, NN);
    scan2_kernel<<<1, 128, 0, stream>>>(bsum, nb1);
    scan3_kernel<<<(NN + 1 + SCAN_B - 1) / SCAN_B, SCAN_B, 0, stream>>>(rowptr, bsum, cursor, NN, NE);

    // scatter (XCD range-partitioned)
    scatter_kernel<<<2048, B256, 0, stream>>>(src, dst, cursor, esrc, NE);

    // layer 0 node transform
    node0_kernel<<<(NN * 64 + B256 - 1) / B256, B256, 0, stream>>>(featb, h64, W0, b0, eps0, h_a, NN);

    // layers 1/2 (782 blocks = 3128 waves -> exactly 2 chunks per wave)
    gin_layer_kernel<<<782, 256, 0, stream>>>(rowptr, esrc, h_a, W1, b1, eps1, h_b);
    gin_layer_kernel<<<782, 256, 0, stream>>>(rowptr, esrc, h_b, W2, b2, eps2, h_a);

    // fused mean-pool + scorer
    pool_scorer_kernel<<<NB / 4, 256, 0, stream>>>(h_a, gstart, Ws1, bs1, Ws2, bs2, out);
}